// Round 3
// baseline (390.492 us; speedup 1.0000x reference)
//
#include <hip/hip_runtime.h>
#include <stdint.h>

typedef uint16_t u16;
typedef u16   u16x8  __attribute__((ext_vector_type(8)));
typedef __bf16 bf16x8 __attribute__((ext_vector_type(8)));
typedef float f32x4  __attribute__((ext_vector_type(4)));

__device__ __forceinline__ float b2f(u16 x) {
    union { uint32_t u; float f; } c; c.u = ((uint32_t)x) << 16; return c.f;
}
__device__ __forceinline__ u16 f2b(float f) {
    union { float f; uint32_t u; } c; c.f = f;
    uint32_t r = c.u + 0x7FFFu + ((c.u >> 16) & 1u);
    return (u16)(r >> 16);
}
__device__ __forceinline__ float silu_f(float x) { return x / (1.f + __expf(-x)); }

// ---------------- dtype probe: are the d_in buffers bf16 or f32? ----------------
// Reads first 8192 u16 words of x and W_in as bf16. f32 buffers have ~uniform
// low-mantissa half-words -> huge/NaN bf16 decodes; real bf16 data stays tiny.
__global__ __launch_bounds__(256) void probe_k(
    const u16* __restrict__ a, const u16* __restrict__ b, int* __restrict__ flag)
{
    __shared__ int cnt;
    if (threadIdx.x == 0) cnt = 0;
    __syncthreads();
    int bad = 0;
    for (int i = threadIdx.x; i < 8192; i += 256) {
        float v1 = b2f(a[i]), v2 = b2f(b[i]);
        if (!(fabsf(v1) < 1000.f)) bad++;   // NaN-safe: NaN fails the <
        if (!(fabsf(v2) < 1000.f)) bad++;
    }
    atomicAdd(&cnt, bad);
    __syncthreads();
    if (threadIdx.x == 0) *flag = (cnt > 0) ? 1 : 0;
}

// canonicalize one input buffer to bf16 (copy raw if bf16, round if f32)
__global__ __launch_bounds__(256) void cvt_k(
    const void* __restrict__ src, u16* __restrict__ dst, int n,
    const int* __restrict__ flag)
{
    int i = blockIdx.x * 256 + threadIdx.x;
    if (i >= n) return;
    dst[i] = (*flag) ? f2b(((const float*)src)[i]) : ((const u16*)src)[i];
}

// final store: bf16 staging -> d_out in the probed dtype, NaN/inf scrubbed
__global__ __launch_bounds__(256) void fstore_k(
    const u16* __restrict__ st, void* __restrict__ dout, int n,
    const int* __restrict__ flag)
{
    int i = blockIdx.x * 256 + threadIdx.x;
    if (i >= n) return;
    float v = b2f(st[i]);
    if (!(fabsf(v) < 1e30f)) v = 0.f;
    if (*flag) ((float*)dout)[i] = v;
    else       ((u16*)dout)[i]   = f2b(v);
}

// ---------------- MFMA NT GEMM: C[m,n] = sum_k A[m,k]*B[n,k] ----------------
// 128x128 tile, BK=32, 4 waves (2x2), each wave 4x4 subtiles of 16x16x32 bf16.
// EPI 0: store bf16 (cols < ncols). EPI 1: store f32 softplus(acc + bias[n]).
template<int EPI>
__global__ __launch_bounds__(256) void gemm_bt(
    const u16* __restrict__ A, const u16* __restrict__ B,
    int K, int lda, int ldb,
    u16* __restrict__ Cb, float* __restrict__ Cf, int ldc, int ncols,
    const u16* __restrict__ bias)
{
    __shared__ __align__(16) u16 lA[128 * 32];
    __shared__ __align__(16) u16 lB[128 * 32];
    const int tid  = threadIdx.x;
    const int wave = tid >> 6, lane = tid & 63;
    const int quad = lane >> 4, l16 = lane & 15;
    const int wm = wave & 1, wn = wave >> 1;
    const int row0 = blockIdx.y * 128, col0 = blockIdx.x * 128;

    f32x4 acc[4][4];
    const f32x4 zf = {0.f, 0.f, 0.f, 0.f};
    for (int i = 0; i < 4; i++) for (int j = 0; j < 4; j++) acc[i][j] = zf;

    const int cl1 = tid, cl2 = tid + 256;
    const int r1 = cl1 >> 2, kg1 = (cl1 & 3) << 3;
    const int r2 = cl2 >> 2, kg2 = (cl2 & 3) << 3;

    const u16* Ap1 = A + (size_t)(row0 + r1) * lda + kg1;
    const u16* Ap2 = A + (size_t)(row0 + r2) * lda + kg2;
    const u16* Bp1 = B + (size_t)(col0 + r1) * ldb + kg1;
    const u16* Bp2 = B + (size_t)(col0 + r2) * ldb + kg2;

    for (int k0 = 0; k0 < K; k0 += 32) {
        u16x8 va1 = *(const u16x8*)(Ap1 + k0);
        u16x8 va2 = *(const u16x8*)(Ap2 + k0);
        u16x8 vb1 = *(const u16x8*)(Bp1 + k0);
        u16x8 vb2 = *(const u16x8*)(Bp2 + k0);
        *(u16x8*)&lA[cl1 * 8] = va1;
        *(u16x8*)&lA[cl2 * 8] = va2;
        *(u16x8*)&lB[cl1 * 8] = vb1;
        *(u16x8*)&lB[cl2 * 8] = vb2;
        __syncthreads();
        bf16x8 af[4], bfr[4];
        for (int i = 0; i < 4; i++)
            af[i] = *(const bf16x8*)&lA[(wm * 64 + i * 16 + l16) * 32 + quad * 8];
        for (int j = 0; j < 4; j++)
            bfr[j] = *(const bf16x8*)&lB[(wn * 64 + j * 16 + l16) * 32 + quad * 8];
        for (int i = 0; i < 4; i++)
            for (int j = 0; j < 4; j++)
                acc[i][j] = __builtin_amdgcn_mfma_f32_16x16x32_bf16(af[i], bfr[j], acc[i][j], 0, 0, 0);
        __syncthreads();
    }

    for (int i = 0; i < 4; i++) {
        int mb = row0 + wm * 64 + i * 16 + quad * 4;
        for (int j = 0; j < 4; j++) {
            int n = col0 + wn * 64 + j * 16 + l16;
            if (n >= ncols) continue;
            if (EPI == 0) {
                for (int v = 0; v < 4; v++)
                    Cb[(size_t)(mb + v) * ldc + n] = f2b(acc[i][j][v]);
            } else {
                float bv = b2f(bias[n]);
                for (int v = 0; v < 4; v++) {
                    float xx = acc[i][j][v] + bv;
                    Cf[(size_t)(mb + v) * ldc + n] =
                        fmaxf(xx, 0.f) + log1pf(__expf(-fabsf(xx)));
                }
            }
        }
    }
}

// ---------------- depthwise causal conv(4) + bias + SiLU ----------------
__global__ __launch_bounds__(256) void conv_silu_k(
    const u16* __restrict__ xr, const u16* __restrict__ cw,
    const u16* __restrict__ cb, u16* __restrict__ u)
{
    int tid = threadIdx.x;
    int bl  = blockIdx.x;       // b*1024 + l
    int l   = bl & 1023;
    int d0  = tid * 8;
    float acc[8];
    u16x8 bias = *(const u16x8*)&cb[d0];
    for (int j = 0; j < 8; j++) acc[j] = b2f(bias[j]);
    union { u16x8 v[4]; u16 s[32]; } wb;
    for (int t = 0; t < 4; t++) wb.v[t] = *(const u16x8*)&cw[d0 * 4 + t * 8];
    for (int t = 0; t < 4; t++) {
        int ls = l - 3 + t;
        if (ls < 0) continue;
        u16x8 xv = *(const u16x8*)&xr[(size_t)(bl - 3 + t) * 4096 + d0];
        for (int j = 0; j < 8; j++) acc[j] += b2f(xv[j]) * b2f(wb.s[j * 4 + t]);
    }
    u16x8 o;
    for (int j = 0; j < 8; j++) o[j] = f2b(silu_f(acc[j]));
    *(u16x8*)&u[(size_t)bl * 2048 + d0] = o;
}

// ---------------- selective scan (per (b,g,d), 32 steps) + gating ----------------
__global__ __launch_bounds__(256) void scan_k(
    const float* __restrict__ delta, const u16* __restrict__ u,
    const u16* __restrict__ xr, const u16* __restrict__ xdbl,
    const u16* __restrict__ latent, const u16* __restrict__ Alog,
    const u16* __restrict__ Dp, u16* __restrict__ yg)
{
    int tid = threadIdx.x;
    int blk = blockIdx.x;
    int dblk = blk & 7, bg = blk >> 3;       // bg = b*32+g
    int d = dblk * 256 + tid;
    __shared__ float Bs[32][16], Cs[32][16];
    for (int idx = tid; idx < 512; idx += 256) {
        int p = idx >> 4, n = idx & 15;
        const u16* xp = &xdbl[(size_t)(bg * 32 + p) * 96];
        Bs[p][n] = b2f(xp[64 + n]);
        Cs[p][n] = b2f(xp[80 + n]);
    }
    __syncthreads();
    float a[16], h[16];
    {
        u16x8 a0 = *(const u16x8*)&Alog[(size_t)d * 16];
        u16x8 a1 = *(const u16x8*)&Alog[(size_t)d * 16 + 8];
        u16x8 l0 = *(const u16x8*)&latent[((size_t)bg * 2048 + d) * 16];
        u16x8 l1 = *(const u16x8*)&latent[((size_t)bg * 2048 + d) * 16 + 8];
        for (int n = 0; n < 8; n++) {
            a[n] = -__expf(b2f(a0[n])); a[8 + n] = -__expf(b2f(a1[n]));
            h[n] = b2f(l0[n]);          h[8 + n] = b2f(l1[n]);
        }
    }
    float Dd = b2f(Dp[d]);
    for (int p = 0; p < 32; p++) {
        size_t row = (size_t)bg * 32 + p;
        float dlt = delta[row * 2048 + d];
        float uu  = b2f(u[row * 2048 + d]);
        float db  = dlt * uu;
        float y = 0.f;
        if (p == 0) {
            for (int n = 0; n < 16; n++) { h[n] += db * Bs[0][n]; y += h[n] * Cs[0][n]; }
        } else {
            for (int n = 0; n < 16; n++) {
                float w = __expf(dlt * a[n]);
                h[n] = w * h[n] + db * Bs[p][n];
                y += h[n] * Cs[p][n];
            }
        }
        float rs = b2f(xr[row * 4096 + 2048 + d]);
        yg[row * 2048 + d] = f2b((y + uu * Dd) * silu_f(rs));
    }
}

// ---------------- latent attention ----------------
__global__ __launch_bounds__(256) void qkv_k(
    const u16* __restrict__ latent, const u16* __restrict__ Wc,
    u16* __restrict__ q, u16* __restrict__ k, u16* __restrict__ v)
{
    __shared__ float Ws[48][16];
    for (int i = threadIdx.x; i < 768; i += 256) Ws[i >> 4][i & 15] = b2f(Wc[i]);
    __syncthreads();
    int gid = blockIdx.x * 256 + threadIdx.x;    // 126976 total
    int d = gid & 2047;
    int bi = gid >> 11;                          // b*31+i
    int b = bi / 31, i = bi - b * 31;
    const u16* lp = &latent[(((size_t)b * 32 + i) * 2048 + d) * 16];
    float lv[16];
    {
        u16x8 l0 = *(const u16x8*)lp, l1 = *(const u16x8*)(lp + 8);
        for (int m = 0; m < 8; m++) { lv[m] = b2f(l0[m]); lv[8 + m] = b2f(l1[m]); }
    }
    u16* outs[3] = {q, k, v};
    for (int pl = 0; pl < 3; pl++) {
        u16x8 o0, o1;
        for (int n = 0; n < 16; n++) {
            float s = 0.f;
            for (int m = 0; m < 16; m++) s += lv[m] * Ws[pl * 16 + n][m];
            if (n < 8) o0[n] = f2b(s); else o1[n - 8] = f2b(s);
        }
        u16* op = outs[pl] + (size_t)bi * 32768 + d * 16;
        *(u16x8*)op = o0; *(u16x8*)(op + 8) = o1;
    }
}

__global__ __launch_bounds__(256) void scores_k(
    const u16* __restrict__ q, const u16* __restrict__ kk, float* __restrict__ sc)
{
    int idx = blockIdx.x;            // b*961 + i*31 + j
    int b = idx / 961, r = idx - b * 961;
    int i = r / 31, j = r - i * 31;
    if (j > i) return;
    const u16* qp = q + ((size_t)b * 31 + i) * 32768;
    const u16* kp = kk + ((size_t)b * 31 + j) * 32768;
    float s = 0.f;
    for (int t = threadIdx.x * 8; t < 32768; t += 2048) {
        u16x8 a = *(const u16x8*)&qp[t];
        u16x8 c = *(const u16x8*)&kp[t];
        for (int e = 0; e < 8; e++) s += b2f(a[e]) * b2f(c[e]);
    }
    for (int off = 32; off; off >>= 1) s += __shfl_xor(s, off);
    __shared__ float red[4];
    if ((threadIdx.x & 63) == 0) red[threadIdx.x >> 6] = s;
    __syncthreads();
    if (threadIdx.x == 0)
        sc[idx] = (red[0] + red[1] + red[2] + red[3]) * 5.5242717e-3f; // 1/sqrt(32768)
}

__global__ __launch_bounds__(64) void softmax_k(
    const float* __restrict__ sc, float* __restrict__ at)
{
    int bi = blockIdx.x;             // 0..61
    int b = bi / 31, i = bi - b * 31;
    int tid = threadIdx.x;
    const float* row = sc + (size_t)b * 961 + i * 31;
    float x = (tid <= i) ? row[tid] : -3.4e38f;
    float mx = x;
    for (int off = 32; off; off >>= 1) mx = fmaxf(mx, __shfl_xor(mx, off));
    float e = (tid <= i) ? __expf(x - mx) : 0.f;
    float sm = e;
    for (int off = 32; off; off >>= 1) sm += __shfl_xor(sm, off);
    if (tid < 31) at[(size_t)b * 961 + i * 31 + tid] = e / sm;
}

__global__ __launch_bounds__(256) void attv_k(
    const float* __restrict__ at, const u16* __restrict__ v, u16* __restrict__ outlat)
{
    int blk = blockIdx.x;
    int chunk = blk & 15, bi = blk >> 4;
    int b = bi / 31, i = bi - b * 31;
    __shared__ float as[31];
    if (threadIdx.x < 31) as[threadIdx.x] = at[(size_t)b * 961 + i * 31 + threadIdx.x];
    __syncthreads();
    int dn = chunk * 2048 + threadIdx.x * 8;
    float acc[8] = {0, 0, 0, 0, 0, 0, 0, 0};
    for (int j = 0; j <= i; j++) {
        u16x8 vv = *(const u16x8*)&v[((size_t)b * 31 + j) * 32768 + dn];
        float aj = as[j];
        for (int e = 0; e < 8; e++) acc[e] += aj * b2f(vv[e]);
    }
    u16x8 o;
    for (int e = 0; e < 8; e++) o[e] = f2b(acc[e]);
    *(u16x8*)&outlat[((size_t)b * 32 + (i + 1)) * 32768 + dn] = o;
}

// ---------------- small helpers ----------------
__global__ __launch_bounds__(256) void prep_wx_k(
    const u16* __restrict__ Wx, u16* __restrict__ Wp)
{
    int gid = blockIdx.x * 256 + threadIdx.x;  // 32768
    int idx = gid * 8;
    int row = idx >> 11, col = idx & 2047;
    u16x8 o;
    if (row < 96) o = *(const u16x8*)&Wx[(size_t)row * 2048 + col];
    else for (int e = 0; e < 8; e++) o[e] = 0;
    *(u16x8*)&Wp[(size_t)idx] = o;
}

__global__ __launch_bounds__(256) void zerolat_k(u16* __restrict__ outlat)
{
    int gid = blockIdx.x * 256 + threadIdx.x;  // 8192
    int idx = gid * 8;
    int b = idx >> 15, off = idx & 32767;
    u16x8 z;
    for (int e = 0; e < 8; e++) z[e] = 0;
    *(u16x8*)&outlat[(size_t)b * 1048576 + off] = z;
}

extern "C" void kernel_launch(void* const* d_in, const int* in_sizes, int n_in,
                              void* d_out, int out_size, void* d_ws, size_t ws_size,
                              hipStream_t stream)
{
    char* ws = (char*)d_ws;
    // canonical bf16 inputs
    u16* cx     = (u16*)(ws + 0);         // 2097152 el
    u16* clat   = (u16*)(ws + 4194304);   // 2097152 el
    u16* cWin   = (u16*)(ws + 8388608);   // 4194304 el
    u16* ccw    = (u16*)(ws + 16777216);  // 8192 el
    u16* ccb    = (u16*)(ws + 16793600);  // 2048 el
    u16* cWx    = (u16*)(ws + 16797696);  // 196608 el
    u16* cWdt   = (u16*)(ws + 17190912);  // 131072 el
    u16* cbdt   = (u16*)(ws + 17453056);  // 2048 el
    u16* cWout  = (u16*)(ws + 17457152);  // 2097152 el
    u16* cAlog  = (u16*)(ws + 21651456);  // 32768 el
    u16* cD     = (u16*)(ws + 21716992);  // 2048 el
    u16* cWc    = (u16*)(ws + 21721088);  // 768 el
    int* flag   = (int*)(ws + 21723136);
    // intermediates
    u16*   wxp   = (u16*)(ws + 21723200);  // 128x2048
    u16*   xdbl  = (u16*)(ws + 22247488);  // 2048x96
    float* sc    = (float*)(ws + 22640704);
    float* at    = (float*)(ws + 22648896);
    u16*   u     = (u16*)(ws + 22657152);  // 2048x2048
    u16*   xr    = (u16*)(ws + 31045760);  // 2048x4096
    float* delta = (float*)(ws + 47822976); // 2048x2048 f32
    // overlays (lifetime-checked):
    u16* yg       = cWin;                  // scan output; W_in dead after G1
    u16* outstage = xr;                    // 4194304 el; xr dead after scan
    u16* qb = (u16*)(ws + 47822976);       // q/k/v overlay delta (dead after scan)
    u16* kb = qb + 2031616;
    u16* vb = kb + 2031616;

    // 1) dtype probe (x and W_in raw words)
    probe_k<<<1, 256, 0, stream>>>((const u16*)d_in[0], (const u16*)d_in[2], flag);
    // 2) canonicalize all inputs to bf16
    struct { const void* s; u16* d; int n; } cv[12] = {
        {d_in[0],  cx,    2097152}, {d_in[1],  clat,  2097152},
        {d_in[2],  cWin,  4194304}, {d_in[3],  ccw,   8192},
        {d_in[4],  ccb,   2048},    {d_in[5],  cWx,   196608},
        {d_in[6],  cWdt,  131072},  {d_in[7],  cbdt,  2048},
        {d_in[8],  cWout, 2097152}, {d_in[9],  cAlog, 32768},
        {d_in[10], cD,    2048},    {d_in[11], cWc,   768},
    };
    for (int i = 0; i < 12; i++)
        cvt_k<<<(cv[i].n + 255) / 256, 256, 0, stream>>>(cv[i].s, cv[i].d, cv[i].n, flag);

    prep_wx_k<<<128, 256, 0, stream>>>(cWx, wxp);
    // xr = x @ W_in^T   (M=2048,N=4096,K=1024)
    gemm_bt<0><<<dim3(32, 16), 256, 0, stream>>>(cx, cWin, 1024, 1024, 1024,
                                                 xr, nullptr, 4096, 4096, nullptr);
    conv_silu_k<<<2048, 256, 0, stream>>>(xr, ccw, ccb, u);
    // x_dbl = u @ W_x^T (M=2048,N=128pad,K=2048) -> store 96 cols
    gemm_bt<0><<<dim3(1, 16), 256, 0, stream>>>(u, wxp, 2048, 2048, 2048,
                                                xdbl, nullptr, 96, 96, nullptr);
    // delta = softplus(x_dbl[:, :64] @ W_dt^T + b_dt) (M=2048,N=2048,K=64)
    gemm_bt<1><<<dim3(16, 16), 256, 0, stream>>>(xdbl, cWdt, 64, 96, 64,
                                                 nullptr, delta, 2048, 2048, cbdt);
    scan_k<<<512, 256, 0, stream>>>(delta, u, xr, xdbl, clat, cAlog, cD, yg);
    // out = yg @ W_out^T (M=2048,N=1024,K=2048) -> outstage[0:2097152)
    gemm_bt<0><<<dim3(8, 16), 256, 0, stream>>>(yg, cWout, 2048, 2048, 2048,
                                                outstage, nullptr, 1024, 1024, nullptr);
    qkv_k<<<496, 256, 0, stream>>>(clat, cWc, qb, kb, vb);
    scores_k<<<1922, 256, 0, stream>>>(qb, kb, sc);
    softmax_k<<<62, 64, 0, stream>>>(sc, at);
    attv_k<<<992, 256, 0, stream>>>(at, vb, outstage + 2097152);
    zerolat_k<<<32, 256, 0, stream>>>(outstage + 2097152);
    // final: staged bf16 -> d_out in probed dtype (NaN-scrubbed)
    fstore_k<<<(out_size + 255) / 256, 256, 0, stream>>>(outstage, d_out, out_size, flag);
}

// Round 4
// 306.854 us; speedup vs baseline: 1.2726x; 1.2726x over previous
//
#include <hip/hip_runtime.h>
#include <stdint.h>

typedef uint16_t u16;
typedef u16   u16x4  __attribute__((ext_vector_type(4)));
typedef u16   u16x8  __attribute__((ext_vector_type(8)));
typedef __bf16 bf16x8 __attribute__((ext_vector_type(8)));
typedef float f32x4  __attribute__((ext_vector_type(4)));

__device__ __forceinline__ float b2f(u16 x) {
    union { uint32_t u; float f; } c; c.u = ((uint32_t)x) << 16; return c.f;
}
__device__ __forceinline__ u16 f2b(float f) {
    union { float f; uint32_t u; } c; c.f = f;
    uint32_t r = c.u + 0x7FFFu + ((c.u >> 16) & 1u);
    return (u16)(r >> 16);
}
__device__ __forceinline__ float silu_f(float x) { return x / (1.f + __expf(-x)); }

// async global->LDS, 16B per lane; lds ptr must be wave-uniform base (HW adds lane*16)
__device__ __forceinline__ void gload16(const u16* g, u16* l) {
    __builtin_amdgcn_global_load_lds(
        (const __attribute__((address_space(1))) void*)(g),
        (__attribute__((address_space(3))) void*)(l), 16, 0, 0);
}

// ---------------- dtype probe: are the d_in buffers bf16 or f32? ----------------
__global__ __launch_bounds__(256) void probe_k(
    const u16* __restrict__ a, const u16* __restrict__ b, int* __restrict__ flag)
{
    __shared__ int cnt;
    if (threadIdx.x == 0) cnt = 0;
    __syncthreads();
    int bad = 0;
    for (int i = threadIdx.x; i < 8192; i += 256) {
        float v1 = b2f(a[i]), v2 = b2f(b[i]);
        if (!(fabsf(v1) < 1000.f)) bad++;   // NaN-safe
        if (!(fabsf(v2) < 1000.f)) bad++;
    }
    atomicAdd(&cnt, bad);
    __syncthreads();
    if (threadIdx.x == 0) *flag = (cnt > 0) ? 1 : 0;
}

// ---------------- unified input canonicalization (13 segments, 4 el/thread) ----------------
struct CvtArgs {
    const void* s[13];
    u16* d[13];
    int cum[14];   // cumulative 4-element-unit offsets
    int total;     // total units
};
__global__ __launch_bounds__(256) void cvt_all_k(CvtArgs a, const int* __restrict__ flag)
{
    int u4 = blockIdx.x * 256 + threadIdx.x;
    if (u4 >= a.total) return;
    int seg = 0;
    while (u4 >= a.cum[seg + 1]) seg++;
    int local = u4 - a.cum[seg];
    const void* s = a.s[seg];
    u16x4 o;
    if (s == nullptr) {
        o[0] = o[1] = o[2] = o[3] = 0;
    } else if (*flag) {
        f32x4 vv = ((const f32x4*)s)[local];
        for (int e = 0; e < 4; e++) o[e] = f2b(vv[e]);
    } else {
        o = ((const u16x4*)s)[local];
    }
    *(u16x4*)(a.d[seg] + (size_t)local * 4) = o;
}

// final store: bf16 staging -> d_out in probed dtype, NaN scrubbed, latent g=0 zeroed
__global__ __launch_bounds__(256) void fstore_k(
    const u16* __restrict__ st, void* __restrict__ dout, int n4,
    const int* __restrict__ flag)
{
    int u4 = blockIdx.x * 256 + threadIdx.x;
    if (u4 >= n4) return;
    int idx = u4 * 4;
    bool zero = false;
    if (idx >= 2097152) {               // lat_out region
        int w = idx - 2097152;
        zero = (((w >> 15) & 31) == 0); // group 0 rows are zeros
    }
    u16x4 sv = *(const u16x4*)&st[idx];
    float v[4];
    for (int e = 0; e < 4; e++) {
        float x = zero ? 0.f : b2f(sv[e]);
        v[e] = (fabsf(x) < 1e30f) ? x : 0.f;
    }
    if (*flag) {
        f32x4 o; for (int e = 0; e < 4; e++) o[e] = v[e];
        ((f32x4*)dout)[u4] = o;
    } else {
        u16x4 o; for (int e = 0; e < 4; e++) o[e] = f2b(v[e]);
        ((u16x4*)dout)[u4] = o;
    }
}

// ---------------- MFMA NT GEMM: C[m,n] = sum_k A[m,k]*B[n,k] ----------------
// 128x128 tile, BK=32, 4 waves (2x2), 4x4 of 16x16x32 bf16 per wave.
// Async global_load_lds staging (m97), swizzled LDS slots (2-way max conflicts).
// k-range = [blockIdx.z*Kc, +Kc). EPI 0: bf16 store (n<ncols). EPI 1: f32
// softplus(acc+bias). EPI 2: f32 raw partial at Cf + z*zslab.
template<int EPI>
__global__ __launch_bounds__(256) void gemm_bt(
    const u16* __restrict__ A, const u16* __restrict__ B,
    int Kc, int lda, int ldb,
    u16* __restrict__ Cb, float* __restrict__ Cf, int ldc, int ncols,
    const u16* __restrict__ bias, size_t zslab)
{
    __shared__ __align__(16) u16 lA[128 * 32];
    __shared__ __align__(16) u16 lB[128 * 32];
    const int tid  = threadIdx.x;
    const int wave = tid >> 6, lane = tid & 63;
    const int quad = lane >> 4, l16 = lane & 15;
    const int wm = wave & 1, wn = wave >> 1;
    const int row0 = blockIdx.y * 128, col0 = blockIdx.x * 128;
    const int kbeg = blockIdx.z * Kc;

    f32x4 acc[4][4];
    const f32x4 zf = {0.f, 0.f, 0.f, 0.f};
    for (int i = 0; i < 4; i++) for (int j = 0; j < 4; j++) acc[i][j] = zf;

    // chunk c (0..511): LDS bytes [c*16, +16) = tile row (c>>2), slot (c&3).
    // slot s of row r holds data k-group q = (s - (r>>1)) & 3  (bank swizzle).
    const int cl1 = tid, cl2 = tid + 256;
    const int r1 = cl1 >> 2, q1 = ((cl1 & 3) - ((r1 >> 1) & 3)) & 3, kg1 = q1 << 3;
    const int r2 = cl2 >> 2, q2 = ((cl2 & 3) - ((r2 >> 1) & 3)) & 3, kg2 = q2 << 3;
    const int c0 = wave << 6;   // wave-uniform chunk base

    const u16* Ap1 = A + (size_t)(row0 + r1) * lda + kg1 + kbeg;
    const u16* Ap2 = A + (size_t)(row0 + r2) * lda + kg2 + kbeg;
    const u16* Bp1 = B + (size_t)(col0 + r1) * ldb + kg1 + kbeg;
    const u16* Bp2 = B + (size_t)(col0 + r2) * ldb + kg2 + kbeg;

    for (int k0 = 0; k0 < Kc; k0 += 32) {
        gload16(Ap1 + k0, &lA[c0 * 8]);
        gload16(Ap2 + k0, &lA[(c0 + 256) * 8]);
        gload16(Bp1 + k0, &lB[c0 * 8]);
        gload16(Bp2 + k0, &lB[(c0 + 256) * 8]);
        __syncthreads();
        bf16x8 af[4], bfr[4];
        for (int i = 0; i < 4; i++) {
            int r = wm * 64 + i * 16 + l16;
            int slot = (quad + (r >> 1)) & 3;
            af[i] = *(const bf16x8*)&lA[r * 32 + slot * 8];
        }
        for (int j = 0; j < 4; j++) {
            int r = wn * 64 + j * 16 + l16;
            int slot = (quad + (r >> 1)) & 3;
            bfr[j] = *(const bf16x8*)&lB[r * 32 + slot * 8];
        }
        for (int i = 0; i < 4; i++)
            for (int j = 0; j < 4; j++)
                acc[i][j] = __builtin_amdgcn_mfma_f32_16x16x32_bf16(af[i], bfr[j], acc[i][j], 0, 0, 0);
        __syncthreads();
    }

    float* dstf = (EPI == 2) ? (Cf + (size_t)blockIdx.z * zslab) : Cf;
    for (int i = 0; i < 4; i++) {
        int mb = row0 + wm * 64 + i * 16 + quad * 4;
        for (int j = 0; j < 4; j++) {
            int n = col0 + wn * 64 + j * 16 + l16;
            if (n >= ncols) continue;
            if (EPI == 0) {
                for (int v = 0; v < 4; v++)
                    Cb[(size_t)(mb + v) * ldc + n] = f2b(acc[i][j][v]);
            } else if (EPI == 1) {
                float bv = b2f(bias[n]);
                for (int v = 0; v < 4; v++) {
                    float xx = acc[i][j][v] + bv;
                    dstf[(size_t)(mb + v) * ldc + n] =
                        fmaxf(xx, 0.f) + log1pf(__expf(-fabsf(xx)));
                }
            } else {
                for (int v = 0; v < 4; v++)
                    dstf[(size_t)(mb + v) * ldc + n] = acc[i][j][v];
            }
        }
    }
}

// reduce split-K partials: dst[m, j..j+3] = bf16(sum_ks part[ks][m][j..j+3])
__global__ __launch_bounds__(256) void redc_k(
    const float* __restrict__ part, u16* __restrict__ dst,
    int KS, int NPAD, int ncols4, int M, int total)
{
    int gid = blockIdx.x * 256 + threadIdx.x;
    if (gid >= total) return;
    int m = gid / ncols4;
    int j = (gid - m * ncols4) * 4;
    f32x4 s = {0.f, 0.f, 0.f, 0.f};
    for (int ks = 0; ks < KS; ks++) {
        f32x4 p = *(const f32x4*)&part[((size_t)ks * M + m) * NPAD + j];
        for (int e = 0; e < 4; e++) s[e] += p[e];
    }
    u16x4 o;
    for (int e = 0; e < 4; e++) o[e] = f2b(s[e]);
    *(u16x4*)&dst[(size_t)m * (ncols4 * 4) + j] = o;
}

// ---------------- depthwise causal conv(4) + bias + SiLU ----------------
__global__ __launch_bounds__(256) void conv_silu_k(
    const u16* __restrict__ xr, const u16* __restrict__ cw,
    const u16* __restrict__ cb, u16* __restrict__ u)
{
    int tid = threadIdx.x;
    int bl  = blockIdx.x;       // b*1024 + l
    int l   = bl & 1023;
    int d0  = tid * 8;
    float acc[8];
    u16x8 bias = *(const u16x8*)&cb[d0];
    for (int j = 0; j < 8; j++) acc[j] = b2f(bias[j]);
    union { u16x8 v[4]; u16 s[32]; } wb;
    for (int t = 0; t < 4; t++) wb.v[t] = *(const u16x8*)&cw[d0 * 4 + t * 8];
    for (int t = 0; t < 4; t++) {
        int ls = l - 3 + t;
        if (ls < 0) continue;
        u16x8 xv = *(const u16x8*)&xr[(size_t)(bl - 3 + t) * 4096 + d0];
        for (int j = 0; j < 8; j++) acc[j] += b2f(xv[j]) * b2f(wb.s[j * 4 + t]);
    }
    u16x8 o;
    for (int j = 0; j < 8; j++) o[j] = f2b(silu_f(acc[j]));
    *(u16x8*)&u[(size_t)bl * 2048 + d0] = o;
}

// ---------------- selective scan (per (b,g,d), 32 steps) + gating ----------------
__global__ __launch_bounds__(256) void scan_k(
    const float* __restrict__ delta, const u16* __restrict__ u,
    const u16* __restrict__ xr, const u16* __restrict__ xdbl,
    const u16* __restrict__ latent, const u16* __restrict__ Alog,
    const u16* __restrict__ Dp, u16* __restrict__ yg)
{
    int tid = threadIdx.x;
    int blk = blockIdx.x;
    int dblk = blk & 7, bg = blk >> 3;       // bg = b*32+g
    int d = dblk * 256 + tid;
    __shared__ float Bs[32][16], Cs[32][16];
    for (int idx = tid; idx < 512; idx += 256) {
        int p = idx >> 4, n = idx & 15;
        const u16* xp = &xdbl[(size_t)(bg * 32 + p) * 96];
        Bs[p][n] = b2f(xp[64 + n]);
        Cs[p][n] = b2f(xp[80 + n]);
    }
    __syncthreads();
    float a[16], h[16];
    {
        u16x8 a0 = *(const u16x8*)&Alog[(size_t)d * 16];
        u16x8 a1 = *(const u16x8*)&Alog[(size_t)d * 16 + 8];
        u16x8 l0 = *(const u16x8*)&latent[((size_t)bg * 2048 + d) * 16];
        u16x8 l1 = *(const u16x8*)&latent[((size_t)bg * 2048 + d) * 16 + 8];
        for (int n = 0; n < 8; n++) {
            a[n] = -__expf(b2f(a0[n])); a[8 + n] = -__expf(b2f(a1[n]));
            h[n] = b2f(l0[n]);          h[8 + n] = b2f(l1[n]);
        }
    }
    float Dd = b2f(Dp[d]);
    for (int p = 0; p < 32; p++) {
        size_t row = (size_t)bg * 32 + p;
        float dlt = delta[row * 2048 + d];
        float uu  = b2f(u[row * 2048 + d]);
        float db  = dlt * uu;
        float y = 0.f;
        if (p == 0) {
            for (int n = 0; n < 16; n++) { h[n] += db * Bs[0][n]; y += h[n] * Cs[0][n]; }
        } else {
            for (int n = 0; n < 16; n++) {
                float w = __expf(dlt * a[n]);
                h[n] = w * h[n] + db * Bs[p][n];
                y += h[n] * Cs[p][n];
            }
        }
        float rs = b2f(xr[row * 4096 + 2048 + d]);
        yg[row * 2048 + d] = f2b((y + uu * Dd) * silu_f(rs));
    }
}

// ---------------- latent attention ----------------
__global__ __launch_bounds__(256) void qkv_k(
    const u16* __restrict__ latent, const u16* __restrict__ Wc,
    u16* __restrict__ q, u16* __restrict__ k, u16* __restrict__ v)
{
    __shared__ float Ws[48][16];
    for (int i = threadIdx.x; i < 768; i += 256) Ws[i >> 4][i & 15] = b2f(Wc[i]);
    __syncthreads();
    int gid = blockIdx.x * 256 + threadIdx.x;    // 126976 total
    int d = gid & 2047;
    int bi = gid >> 11;                          // b*31+i
    int b = bi / 31, i = bi - b * 31;
    const u16* lp = &latent[(((size_t)b * 32 + i) * 2048 + d) * 16];
    float lv[16];
    {
        u16x8 l0 = *(const u16x8*)lp, l1 = *(const u16x8*)(lp + 8);
        for (int m = 0; m < 8; m++) { lv[m] = b2f(l0[m]); lv[8 + m] = b2f(l1[m]); }
    }
    u16* outs[3] = {q, k, v};
    for (int pl = 0; pl < 3; pl++) {
        u16x8 o0, o1;
        for (int n = 0; n < 16; n++) {
            float s = 0.f;
            for (int m = 0; m < 16; m++) s += lv[m] * Ws[pl * 16 + n][m];
            if (n < 8) o0[n] = f2b(s); else o1[n - 8] = f2b(s);
        }
        u16* op = outs[pl] + (size_t)bi * 32768 + d * 16;
        *(u16x8*)op = o0; *(u16x8*)(op + 8) = o1;
    }
}

__global__ __launch_bounds__(256) void scores_k(
    const u16* __restrict__ q, const u16* __restrict__ kk, float* __restrict__ sc)
{
    int idx = blockIdx.x;            // b*961 + i*31 + j
    int b = idx / 961, r = idx - b * 961;
    int i = r / 31, j = r - i * 31;
    if (j > i) return;
    const u16* qp = q + ((size_t)b * 31 + i) * 32768;
    const u16* kp = kk + ((size_t)b * 31 + j) * 32768;
    float s = 0.f;
    for (int t = threadIdx.x * 8; t < 32768; t += 2048) {
        u16x8 a = *(const u16x8*)&qp[t];
        u16x8 c = *(const u16x8*)&kp[t];
        for (int e = 0; e < 8; e++) s += b2f(a[e]) * b2f(c[e]);
    }
    for (int off = 32; off; off >>= 1) s += __shfl_xor(s, off);
    __shared__ float red[4];
    if ((threadIdx.x & 63) == 0) red[threadIdx.x >> 6] = s;
    __syncthreads();
    if (threadIdx.x == 0)
        sc[idx] = (red[0] + red[1] + red[2] + red[3]) * 5.5242717e-3f; // 1/sqrt(32768)
}

__global__ __launch_bounds__(64) void softmax_k(
    const float* __restrict__ sc, float* __restrict__ at)
{
    int bi = blockIdx.x;             // 0..61
    int b = bi / 31, i = bi - b * 31;
    int tid = threadIdx.x;
    const float* row = sc + (size_t)b * 961 + i * 31;
    float x = (tid <= i) ? row[tid] : -3.4e38f;
    float mx = x;
    for (int off = 32; off; off >>= 1) mx = fmaxf(mx, __shfl_xor(mx, off));
    float e = (tid <= i) ? __expf(x - mx) : 0.f;
    float sm = e;
    for (int off = 32; off; off >>= 1) sm += __shfl_xor(sm, off);
    if (tid < 31) at[(size_t)b * 961 + i * 31 + tid] = e / sm;
}

__global__ __launch_bounds__(256) void attv_k(
    const float* __restrict__ at, const u16* __restrict__ v, u16* __restrict__ outlat)
{
    int blk = blockIdx.x;
    int chunk = blk & 15, bi = blk >> 4;
    int b = bi / 31, i = bi - b * 31;
    __shared__ float as[31];
    if (threadIdx.x < 31) as[threadIdx.x] = at[(size_t)b * 961 + i * 31 + threadIdx.x];
    __syncthreads();
    int dn = chunk * 2048 + threadIdx.x * 8;
    float acc[8] = {0, 0, 0, 0, 0, 0, 0, 0};
    for (int j = 0; j <= i; j++) {
        u16x8 vv = *(const u16x8*)&v[((size_t)b * 31 + j) * 32768 + dn];
        float aj = as[j];
        for (int e = 0; e < 8; e++) acc[e] += aj * b2f(vv[e]);
    }
    u16x8 o;
    for (int e = 0; e < 8; e++) o[e] = f2b(acc[e]);
    *(u16x8*)&outlat[((size_t)b * 32 + (i + 1)) * 32768 + dn] = o;
}

extern "C" void kernel_launch(void* const* d_in, const int* in_sizes, int n_in,
                              void* d_out, int out_size, void* d_ws, size_t ws_size,
                              hipStream_t stream)
{
    char* ws = (char*)d_ws;
    // canonical bf16 inputs
    u16* cx    = (u16*)(ws + 0);          // 2097152 el
    u16* clat  = (u16*)(ws + 4194304);    // 2097152 el
    u16* cWin  = (u16*)(ws + 8388608);    // 4194304 el
    u16* ccw   = (u16*)(ws + 16777216);   // 8192
    u16* ccb   = (u16*)(ws + 16793600);   // 2048
    u16* wxp   = (u16*)(ws + 16797696);   // 128x2048 (W_x converted + zero pad)
    u16* cWdt  = (u16*)(ws + 17321984);   // 131072
    u16* cbdt  = (u16*)(ws + 17584128);   // 2048
    u16* cWout = (u16*)(ws + 17588224);   // 2097152
    u16* cAlog = (u16*)(ws + 21782528);   // 32768
    u16* cD    = (u16*)(ws + 21848064);   // 2048
    u16* cWc   = (u16*)(ws + 21852160);   // 768
    int* flag  = (int*)(ws + 21853696);
    // intermediates
    u16*   xdbl = (u16*)(ws + 21853760);  // 2048x96 bf16
    float* sc   = (float*)(ws + 22246976);
    float* at   = (float*)(ws + 22255168);
    u16*   u    = (u16*)(ws + 22263360);  // 2048x2048 bf16
    u16*   xr   = (u16*)(ws + 30651968);  // 2048x4096 bf16
    // 16 MB region with sequential lifetimes:
    //   xdbl_part (split-K slab) -> delta f32 -> q/k/v -> out_part (split-K slab)
    char*  big  = ws + 47429184;
    float* xdbl_part = (float*)big;       // 16 x 2048 x 128 f32
    float* delta     = (float*)big;       // 2048 x 2048 f32
    u16*   qb        = (u16*)big;         // 3 x 2031616 bf16
    u16*   kb        = qb + 2031616;
    u16*   vb        = kb + 2031616;
    float* out_part  = (float*)big;       // 2 x 2048 x 1024 f32
    // overlays
    u16* yg       = cWin;                 // W_in dead after G1
    u16* outstage = xr;                   // xr dead after scan

    // 1) dtype probe
    probe_k<<<1, 256, 0, stream>>>((const u16*)d_in[0], (const u16*)d_in[2], flag);

    // 2) canonicalize all inputs (one kernel; W_x lands padded in wxp)
    CvtArgs ca;
    const void* srcs[13] = { d_in[0], d_in[1], d_in[2], d_in[3], d_in[4],
                             d_in[5], nullptr, d_in[6], d_in[7], d_in[8],
                             d_in[9], d_in[10], d_in[11] };
    u16* dsts[13] = { cx, clat, cWin, ccw, ccb,
                      wxp, wxp + 196608, cWdt, cbdt, cWout,
                      cAlog, cD, cWc };
    int ns[13] = { 2097152, 2097152, 4194304, 8192, 2048,
                   196608, 65536, 131072, 2048, 2097152,
                   32768, 2048, 768 };
    int cum = 0;
    for (int i = 0; i < 13; i++) {
        ca.s[i] = srcs[i]; ca.d[i] = dsts[i];
        ca.cum[i] = cum; cum += ns[i] / 4;
    }
    ca.cum[13] = cum; ca.total = cum;     // 2,731,712 units
    cvt_all_k<<<(cum + 255) / 256, 256, 0, stream>>>(ca, flag);

    // 3) xr = x @ W_in^T   (M=2048,N=4096,K=1024)
    gemm_bt<0><<<dim3(32, 16, 1), 256, 0, stream>>>(cx, cWin, 1024, 1024, 1024,
                                                    xr, nullptr, 4096, 4096, nullptr, 0);
    // 4) depthwise conv + SiLU
    conv_silu_k<<<2048, 256, 0, stream>>>(xr, ccw, ccb, u);
    // 5) x_dbl = u @ W_x^T, split-K 16 (M=2048,N=128pad,K=2048)
    gemm_bt<2><<<dim3(1, 16, 16), 256, 0, stream>>>(u, wxp, 128, 2048, 2048,
                                                    nullptr, xdbl_part, 128, 128,
                                                    nullptr, (size_t)2048 * 128);
    redc_k<<<192, 256, 0, stream>>>(xdbl_part, xdbl, 16, 128, 24, 2048, 49152);
    // 6) delta = softplus(x_dbl[:,:64] @ W_dt^T + b_dt) (M=2048,N=2048,K=64)
    gemm_bt<1><<<dim3(16, 16, 1), 256, 0, stream>>>(xdbl, cWdt, 64, 96, 64,
                                                    nullptr, delta, 2048, 2048, cbdt, 0);
    // 7) selective scan + gating
    scan_k<<<512, 256, 0, stream>>>(delta, u, xr, xdbl, clat, cAlog, cD, yg);
    // 8) latent attention (uses big region; must finish before out_part)
    qkv_k<<<496, 256, 0, stream>>>(clat, cWc, qb, kb, vb);
    scores_k<<<1922, 256, 0, stream>>>(qb, kb, sc);
    softmax_k<<<62, 64, 0, stream>>>(sc, at);
    attv_k<<<992, 256, 0, stream>>>(at, vb, outstage + 2097152);
    // 9) out = yg @ W_out^T, split-K 2 (M=2048,N=1024,K=2048)
    gemm_bt<2><<<dim3(8, 16, 2), 256, 0, stream>>>(yg, cWout, 1024, 2048, 2048,
                                                   nullptr, out_part, 1024, 1024,
                                                   nullptr, (size_t)2048 * 1024);
    redc_k<<<2048, 256, 0, stream>>>(out_part, outstage, 2, 1024, 256, 2048, 524288);
    // 10) final store (dtype dispatch + NaN scrub + latent g=0 zeros)
    fstore_k<<<4096, 256, 0, stream>>>(outstage, d_out, 1048576, flag);
}

// Round 5
// 273.071 us; speedup vs baseline: 1.4300x; 1.1237x over previous
//
#include <hip/hip_runtime.h>
#include <stdint.h>

typedef uint16_t u16;
typedef u16   u16x4  __attribute__((ext_vector_type(4)));
typedef u16   u16x8  __attribute__((ext_vector_type(8)));
typedef __bf16 bf16x8 __attribute__((ext_vector_type(8)));
typedef float f32x4  __attribute__((ext_vector_type(4)));

__device__ __forceinline__ float b2f(u16 x) {
    union { uint32_t u; float f; } c; c.u = ((uint32_t)x) << 16; return c.f;
}
__device__ __forceinline__ u16 f2b(float f) {
    union { float f; uint32_t u; } c; c.f = f;
    uint32_t r = c.u + 0x7FFFu + ((c.u >> 16) & 1u);
    return (u16)(r >> 16);
}
__device__ __forceinline__ float silu_f(float x) { return x / (1.f + __expf(-x)); }

__device__ __forceinline__ void gload16(const u16* g, u16* l) {
    __builtin_amdgcn_global_load_lds(
        (const __attribute__((address_space(1))) void*)(g),
        (__attribute__((address_space(3))) void*)(l), 16, 0, 0);
}

// per-block dtype flag: 1 = inputs are f32, 0 = bf16. Reads first 256 raw
// words of x; f32 low-mantissa halves decode as huge/NaN bf16 w.p. ~0.47 each.
// Requires blockDim 256; contains a barrier (call unconditionally, first).
__device__ __forceinline__ int dtype_flag_block(const u16* __restrict__ xraw) {
    __shared__ int bad;
    if (threadIdx.x == 0) bad = 0;
    __syncthreads();
    float v = b2f(xraw[threadIdx.x]);
    if (!(fabsf(v) < 1000.f)) atomicAdd(&bad, 1);   // NaN-safe
    __syncthreads();
    return bad;
}

// ---------------- unified input canonicalization (13 segments, 4 el/thread) ----------------
struct CvtArgs {
    const void* s[13];
    u16* d[13];
    int cum[14];
    int total;
};
__global__ __launch_bounds__(256) void cvt_all_k(CvtArgs a, const u16* __restrict__ xraw)
{
    int flag = dtype_flag_block(xraw);
    int u4 = blockIdx.x * 256 + threadIdx.x;
    if (u4 >= a.total) return;
    int seg = 0;
    while (u4 >= a.cum[seg + 1]) seg++;
    int local = u4 - a.cum[seg];
    const void* s = a.s[seg];
    u16x4 o;
    if (s == nullptr) {
        o[0] = o[1] = o[2] = o[3] = 0;
    } else if (flag) {
        f32x4 vv = ((const f32x4*)s)[local];
        for (int e = 0; e < 4; e++) o[e] = f2b(vv[e]);
    } else {
        o = ((const u16x4*)s)[local];
    }
    *(u16x4*)(a.d[seg] + (size_t)local * 4) = o;
}

// ---------------- MFMA NT GEMM: C[m,n] = sum_k A[m,k]*B[n,k] ----------------
// 128x128 tile, BK=64, 4 waves (2x2), 4x4 of 16x16x32 bf16 per wave, 2 k-halves
// per BK-tile. Async global_load_lds staging, 8-slot swizzled LDS rows.
// EPI 0: bf16 store (n<ncols). EPI 1: f32 softplus(acc+bias). EPI 2: f32 raw
// partial at Cf + z*zslab.  Kc must be a multiple of 64.
template<int EPI>
__global__ __launch_bounds__(256) void gemm_bt(
    const u16* __restrict__ A, const u16* __restrict__ B,
    int Kc, int lda, int ldb,
    u16* __restrict__ Cb, float* __restrict__ Cf, int ldc, int ncols,
    const u16* __restrict__ bias, size_t zslab)
{
    __shared__ __align__(16) u16 lA[128 * 64];
    __shared__ __align__(16) u16 lB[128 * 64];
    const int tid  = threadIdx.x;
    const int wave = tid >> 6, lane = tid & 63;
    const int quad = lane >> 4, l16 = lane & 15;
    const int wm = wave & 1, wn = wave >> 1;
    const int row0 = blockIdx.y * 128, col0 = blockIdx.x * 128;
    const int kbeg = blockIdx.z * Kc;

    f32x4 acc[4][4];
    const f32x4 zf = {0.f, 0.f, 0.f, 0.f};
    for (int i = 0; i < 4; i++) for (int j = 0; j < 4; j++) acc[i][j] = zf;

    // staging: chunk c in [0,1024) = 16B at lX[c*8]; row r=c>>3, slot s=c&7.
    // slot s of row r holds k-group q = (s - (r>>1)) & 7 (bank swizzle).
    // per t: chunks t*256 + wave*64 + lane  (wave-uniform LDS base + lane*16B)
    const u16* Ap[4]; const u16* Bp[4]; int lbase[4];
    for (int t = 0; t < 4; t++) {
        int c = t * 256 + tid;
        int r = c >> 3, s = c & 7;
        int q = (s - (r >> 1)) & 7;
        Ap[t] = A + (size_t)(row0 + r) * lda + q * 8 + kbeg;
        Bp[t] = B + (size_t)(col0 + r) * ldb + q * 8 + kbeg;
        lbase[t] = (t * 256 + wave * 64) * 8;
    }

    for (int k0 = 0; k0 < Kc; k0 += 64) {
        for (int t = 0; t < 4; t++) gload16(Ap[t] + k0, &lA[lbase[t]]);
        for (int t = 0; t < 4; t++) gload16(Bp[t] + k0, &lB[lbase[t]]);
        __syncthreads();
        for (int half = 0; half < 2; half++) {
            bf16x8 af[4], bfr[4];
            for (int i = 0; i < 4; i++) {
                int r = wm * 64 + i * 16 + l16;
                int s = (half * 4 + quad + (r >> 1)) & 7;
                af[i] = *(const bf16x8*)&lA[r * 64 + s * 8];
            }
            for (int j = 0; j < 4; j++) {
                int r = wn * 64 + j * 16 + l16;
                int s = (half * 4 + quad + (r >> 1)) & 7;
                bfr[j] = *(const bf16x8*)&lB[r * 64 + s * 8];
            }
            for (int i = 0; i < 4; i++)
                for (int j = 0; j < 4; j++)
                    acc[i][j] = __builtin_amdgcn_mfma_f32_16x16x32_bf16(af[i], bfr[j], acc[i][j], 0, 0, 0);
        }
        __syncthreads();
    }

    float* dstf = (EPI == 2) ? (Cf + (size_t)blockIdx.z * zslab) : Cf;
    for (int i = 0; i < 4; i++) {
        int mb = row0 + wm * 64 + i * 16 + quad * 4;
        for (int j = 0; j < 4; j++) {
            int n = col0 + wn * 64 + j * 16 + l16;
            if (n >= ncols) continue;
            if (EPI == 0) {
                for (int v = 0; v < 4; v++)
                    Cb[(size_t)(mb + v) * ldc + n] = f2b(acc[i][j][v]);
            } else if (EPI == 1) {
                float bv = b2f(bias[n]);
                for (int v = 0; v < 4; v++) {
                    float xx = acc[i][j][v] + bv;
                    dstf[(size_t)(mb + v) * ldc + n] =
                        fmaxf(xx, 0.f) + log1pf(__expf(-fabsf(xx)));
                }
            } else {
                for (int v = 0; v < 4; v++)
                    dstf[(size_t)(mb + v) * ldc + n] = acc[i][j][v];
            }
        }
    }
}

// reduce split-K partials -> bf16 (used for xdbl)
__global__ __launch_bounds__(256) void redc_k(
    const float* __restrict__ part, u16* __restrict__ dst,
    int KS, int NPAD, int ncols4, int M, int total)
{
    int gid = blockIdx.x * 256 + threadIdx.x;
    if (gid >= total) return;
    int m = gid / ncols4;
    int j = (gid - m * ncols4) * 4;
    f32x4 s = {0.f, 0.f, 0.f, 0.f};
    for (int ks = 0; ks < KS; ks++) {
        f32x4 p = *(const f32x4*)&part[((size_t)ks * M + m) * NPAD + j];
        for (int e = 0; e < 4; e++) s[e] += p[e];
    }
    u16x4 o;
    for (int e = 0; e < 4; e++) o[e] = f2b(s[e]);
    *(u16x4*)&dst[(size_t)m * (ncols4 * 4) + j] = o;
}

// reduce out-GEMM split-K partials (KS=4, N=1024) -> d_out directly, dtype+scrub
__global__ __launch_bounds__(256) void redout_k(
    const float* __restrict__ part, void* __restrict__ dout,
    const u16* __restrict__ xraw)
{
    int flag = dtype_flag_block(xraw);
    int gid = blockIdx.x * 256 + threadIdx.x;   // 524288 total
    int m = gid >> 8;
    int j = (gid & 255) * 4;
    f32x4 s = {0.f, 0.f, 0.f, 0.f};
    for (int ks = 0; ks < 4; ks++) {
        f32x4 p = *(const f32x4*)&part[((size_t)ks * 2048 + m) * 1024 + j];
        for (int e = 0; e < 4; e++) s[e] += p[e];
    }
    for (int e = 0; e < 4; e++) if (!(fabsf(s[e]) < 1e30f)) s[e] = 0.f;
    if (flag) {
        ((f32x4*)dout)[(size_t)m * 256 + (j >> 2)] = s;
    } else {
        u16x4 o;
        for (int e = 0; e < 4; e++) o[e] = f2b(s[e]);
        ((u16x4*)dout)[(size_t)m * 256 + (j >> 2)] = o;
    }
}

// ---------------- depthwise causal conv(4) + bias + SiLU ----------------
__global__ __launch_bounds__(256) void conv_silu_k(
    const u16* __restrict__ xr, const u16* __restrict__ cw,
    const u16* __restrict__ cb, u16* __restrict__ u)
{
    int tid = threadIdx.x;
    int bl  = blockIdx.x;       // b*1024 + l
    int l   = bl & 1023;
    int d0  = tid * 8;
    float acc[8];
    u16x8 bias = *(const u16x8*)&cb[d0];
    for (int j = 0; j < 8; j++) acc[j] = b2f(bias[j]);
    union { u16x8 v[4]; u16 s[32]; } wb;
    for (int t = 0; t < 4; t++) wb.v[t] = *(const u16x8*)&cw[d0 * 4 + t * 8];
    for (int t = 0; t < 4; t++) {
        int ls = l - 3 + t;
        if (ls < 0) continue;
        u16x8 xv = *(const u16x8*)&xr[(size_t)(bl - 3 + t) * 4096 + d0];
        for (int j = 0; j < 8; j++) acc[j] += b2f(xv[j]) * b2f(wb.s[j * 4 + t]);
    }
    u16x8 o;
    for (int j = 0; j < 8; j++) o[j] = f2b(silu_f(acc[j]));
    *(u16x8*)&u[(size_t)bl * 2048 + d0] = o;
}

// ---------------- selective scan (per (b,g,d), 32 steps) + gating ----------------
__global__ __launch_bounds__(256) void scan_k(
    const float* __restrict__ delta, const u16* __restrict__ u,
    const u16* __restrict__ xr, const u16* __restrict__ xdbl,
    const u16* __restrict__ latent, const u16* __restrict__ Alog,
    const u16* __restrict__ Dp, u16* __restrict__ yg)
{
    int tid = threadIdx.x;
    int blk = blockIdx.x;
    int dblk = blk & 7, bg = blk >> 3;       // bg = b*32+g
    int d = dblk * 256 + tid;
    __shared__ float Bs[32][16], Cs[32][16];
    for (int idx = tid; idx < 512; idx += 256) {
        int p = idx >> 4, n = idx & 15;
        const u16* xp = &xdbl[(size_t)(bg * 32 + p) * 96];
        Bs[p][n] = b2f(xp[64 + n]);
        Cs[p][n] = b2f(xp[80 + n]);
    }
    __syncthreads();
    float a[16], h[16];
    {
        u16x8 a0 = *(const u16x8*)&Alog[(size_t)d * 16];
        u16x8 a1 = *(const u16x8*)&Alog[(size_t)d * 16 + 8];
        u16x8 l0 = *(const u16x8*)&latent[((size_t)bg * 2048 + d) * 16];
        u16x8 l1 = *(const u16x8*)&latent[((size_t)bg * 2048 + d) * 16 + 8];
        for (int n = 0; n < 8; n++) {
            a[n] = -__expf(b2f(a0[n])); a[8 + n] = -__expf(b2f(a1[n]));
            h[n] = b2f(l0[n]);          h[8 + n] = b2f(l1[n]);
        }
    }
    float Dd = b2f(Dp[d]);
    for (int p = 0; p < 32; p++) {
        size_t row = (size_t)bg * 32 + p;
        float dlt = delta[row * 2048 + d];
        float uu  = b2f(u[row * 2048 + d]);
        float db  = dlt * uu;
        float y = 0.f;
        if (p == 0) {
            for (int n = 0; n < 16; n++) { h[n] += db * Bs[0][n]; y += h[n] * Cs[0][n]; }
        } else {
            for (int n = 0; n < 16; n++) {
                float w = __expf(dlt * a[n]);
                h[n] = w * h[n] + db * Bs[p][n];
                y += h[n] * Cs[p][n];
            }
        }
        float rs = b2f(xr[row * 4096 + 2048 + d]);
        yg[row * 2048 + d] = f2b((y + uu * Dd) * silu_f(rs));
    }
}

// ---------------- latent attention ----------------
__global__ __launch_bounds__(256) void qkv_k(
    const u16* __restrict__ latent, const u16* __restrict__ Wc,
    u16* __restrict__ q, u16* __restrict__ k, u16* __restrict__ v)
{
    __shared__ float Ws[48][16];
    for (int i = threadIdx.x; i < 768; i += 256) Ws[i >> 4][i & 15] = b2f(Wc[i]);
    __syncthreads();
    int gid = blockIdx.x * 256 + threadIdx.x;    // 126976 total
    int d = gid & 2047;
    int bi = gid >> 11;                          // b*31+i
    int b = bi / 31, i = bi - b * 31;
    const u16* lp = &latent[(((size_t)b * 32 + i) * 2048 + d) * 16];
    float lv[16];
    {
        u16x8 l0 = *(const u16x8*)lp, l1 = *(const u16x8*)(lp + 8);
        for (int m = 0; m < 8; m++) { lv[m] = b2f(l0[m]); lv[8 + m] = b2f(l1[m]); }
    }
    u16* outs[3] = {q, k, v};
    for (int pl = 0; pl < 3; pl++) {
        u16x8 o0, o1;
        for (int n = 0; n < 16; n++) {
            float s = 0.f;
            for (int m = 0; m < 16; m++) s += lv[m] * Ws[pl * 16 + n][m];
            if (n < 8) o0[n] = f2b(s); else o1[n - 8] = f2b(s);
        }
        u16* op = outs[pl] + (size_t)bi * 32768 + d * 16;
        *(u16x8*)op = o0; *(u16x8*)(op + 8) = o1;
    }
}

__global__ __launch_bounds__(256) void scores_k(
    const u16* __restrict__ q, const u16* __restrict__ kk, float* __restrict__ sc)
{
    int idx = blockIdx.x;            // b*961 + i*31 + j
    int b = idx / 961, r = idx - b * 961;
    int i = r / 31, j = r - i * 31;
    if (j > i) return;
    const u16* qp = q + ((size_t)b * 31 + i) * 32768;
    const u16* kp = kk + ((size_t)b * 31 + j) * 32768;
    float s = 0.f;
    for (int t = threadIdx.x * 8; t < 32768; t += 2048) {
        u16x8 a = *(const u16x8*)&qp[t];
        u16x8 c = *(const u16x8*)&kp[t];
        for (int e = 0; e < 8; e++) s += b2f(a[e]) * b2f(c[e]);
    }
    for (int off = 32; off; off >>= 1) s += __shfl_xor(s, off);
    __shared__ float red[4];
    if ((threadIdx.x & 63) == 0) red[threadIdx.x >> 6] = s;
    __syncthreads();
    if (threadIdx.x == 0)
        sc[idx] = (red[0] + red[1] + red[2] + red[3]) * 5.5242717e-3f; // 1/sqrt(32768)
}

// attn@v with inline softmax + g=0 zero rows, direct dtype-dispatched d_out write
__global__ __launch_bounds__(256) void attv_k(
    const float* __restrict__ sc, const u16* __restrict__ v,
    void* __restrict__ dout, const u16* __restrict__ xraw)
{
    int flag = dtype_flag_block(xraw);
    int blk = blockIdx.x;              // 16 chunks x 64 (b, row) pairs
    int chunk = blk & 15, bi = blk >> 4;
    int b = bi >> 5, i = (bi & 31) - 1;   // i = -1 -> zero row (group 0)
    __shared__ float as[32];
    if (i >= 0 && threadIdx.x < 64) {
        float x = (threadIdx.x <= i) ? sc[(size_t)b * 961 + i * 31 + threadIdx.x] : -3.4e38f;
        float mx = x;
        for (int off = 32; off; off >>= 1) mx = fmaxf(mx, __shfl_xor(mx, off));
        float e = (threadIdx.x <= i) ? __expf(x - mx) : 0.f;
        float sm = e;
        for (int off = 32; off; off >>= 1) sm += __shfl_xor(sm, off);
        if (threadIdx.x < 32) as[threadIdx.x] = e / sm;
    }
    __syncthreads();
    int dn = chunk * 2048 + threadIdx.x * 8;
    float acc[8] = {0, 0, 0, 0, 0, 0, 0, 0};
    if (i >= 0) {
        for (int j = 0; j <= i; j++) {
            u16x8 vv = *(const u16x8*)&v[((size_t)b * 31 + j) * 32768 + dn];
            float aj = as[j];
            for (int e = 0; e < 8; e++) acc[e] += aj * b2f(vv[e]);
        }
        for (int e = 0; e < 8; e++) if (!(fabsf(acc[e]) < 1e30f)) acc[e] = 0.f;
    }
    size_t ofs = 2097152 + ((size_t)b * 32 + (i + 1)) * 32768 + dn;
    if (flag) {
        f32x4 o0, o1;
        for (int e = 0; e < 4; e++) { o0[e] = acc[e]; o1[e] = acc[4 + e]; }
        *(f32x4*)((float*)dout + ofs) = o0;
        *(f32x4*)((float*)dout + ofs + 4) = o1;
    } else {
        u16x8 o;
        for (int e = 0; e < 8; e++) o[e] = f2b(acc[e]);
        *(u16x8*)((u16*)dout + ofs) = o;
    }
}

extern "C" void kernel_launch(void* const* d_in, const int* in_sizes, int n_in,
                              void* d_out, int out_size, void* d_ws, size_t ws_size,
                              hipStream_t stream)
{
    char* ws = (char*)d_ws;
    const u16* xraw = (const u16*)d_in[0];
    // canonical bf16 inputs
    u16* cx    = (u16*)(ws + 0);
    u16* clat  = (u16*)(ws + 4194304);
    u16* cWin  = (u16*)(ws + 8388608);
    u16* ccw   = (u16*)(ws + 16777216);
    u16* ccb   = (u16*)(ws + 16793600);
    u16* wxp   = (u16*)(ws + 16797696);   // 128x2048 (W_x + zero pad)
    u16* cWdt  = (u16*)(ws + 17321984);
    u16* cbdt  = (u16*)(ws + 17584128);
    u16* cWout = (u16*)(ws + 17588224);
    u16* cAlog = (u16*)(ws + 21782528);
    u16* cD    = (u16*)(ws + 21848064);
    u16* cWc   = (u16*)(ws + 21852160);
    // intermediates (all private; ws is ~268 MB)
    u16*   xdbl      = (u16*)(ws + 21853760);   // 2048x96 bf16
    float* sc        = (float*)(ws + 22246976); // 1922 f32
    u16*   u         = (u16*)(ws + 22263360);   // 2048x2048 bf16
    u16*   xr        = (u16*)(ws + 30651968);   // 2048x4096 bf16
    u16*   yg        = (u16*)(ws + 47429184);   // 2048x2048 bf16
    float* delta     = (float*)(ws + 55817792); // 2048x2048 f32
    float* xdbl_part = (float*)(ws + 72595008); // 16x2048x128 f32
    u16*   qb        = (u16*)(ws + 89372224);   // 3x 2031616 bf16
    u16*   kb        = qb + 2031616;
    u16*   vb        = kb + 2031616;
    float* out_part  = (float*)(ws + 101561920); // 4x2048x1024 f32 (ends ~135 MB)

    // 1) canonicalize all inputs to bf16 (self-contained dtype flag)
    CvtArgs ca;
    const void* srcs[13] = { d_in[0], d_in[1], d_in[2], d_in[3], d_in[4],
                             d_in[5], nullptr, d_in[6], d_in[7], d_in[8],
                             d_in[9], d_in[10], d_in[11] };
    u16* dsts[13] = { cx, clat, cWin, ccw, ccb,
                      wxp, wxp + 196608, cWdt, cbdt, cWout,
                      cAlog, cD, cWc };
    int ns[13] = { 2097152, 2097152, 4194304, 8192, 2048,
                   196608, 65536, 131072, 2048, 2097152,
                   32768, 2048, 768 };
    int cum = 0;
    for (int i = 0; i < 13; i++) {
        ca.s[i] = srcs[i]; ca.d[i] = dsts[i];
        ca.cum[i] = cum; cum += ns[i] / 4;
    }
    ca.cum[13] = cum; ca.total = cum;    // 2,731,712 units
    cvt_all_k<<<(cum + 255) / 256, 256, 0, stream>>>(ca, xraw);

    // 2) xr = x @ W_in^T   (M=2048,N=4096,K=1024)
    gemm_bt<0><<<dim3(32, 16, 1), 256, 0, stream>>>(cx, cWin, 1024, 1024, 1024,
                                                    xr, nullptr, 4096, 4096, nullptr, 0);
    // 3) depthwise conv + SiLU
    conv_silu_k<<<2048, 256, 0, stream>>>(xr, ccw, ccb, u);
    // 4) x_dbl = u @ W_x^T, split-K 16 (M=2048,N=128pad,K=2048)
    gemm_bt<2><<<dim3(1, 16, 16), 256, 0, stream>>>(u, wxp, 128, 2048, 2048,
                                                    nullptr, xdbl_part, 128, 128,
                                                    nullptr, (size_t)2048 * 128);
    redc_k<<<192, 256, 0, stream>>>(xdbl_part, xdbl, 16, 128, 24, 2048, 49152);
    // 5) delta = softplus(x_dbl[:,:64] @ W_dt^T + b_dt) (M=2048,N=2048,K=64)
    gemm_bt<1><<<dim3(16, 16, 1), 256, 0, stream>>>(xdbl, cWdt, 64, 96, 64,
                                                    nullptr, delta, 2048, 2048, cbdt, 0);
    // 6) selective scan + gating
    scan_k<<<512, 256, 0, stream>>>(delta, u, xr, xdbl, clat, cAlog, cD, yg);
    // 7) latent attention -> d_out[2097152:]
    qkv_k<<<496, 256, 0, stream>>>(clat, cWc, qb, kb, vb);
    scores_k<<<1922, 256, 0, stream>>>(qb, kb, sc);
    attv_k<<<1024, 256, 0, stream>>>(sc, vb, d_out, xraw);
    // 8) out = yg @ W_out^T, split-K 4 (M=2048,N=1024,K=2048) -> d_out[0:2097152]
    gemm_bt<2><<<dim3(8, 16, 4), 256, 0, stream>>>(yg, cWout, 512, 2048, 2048,
                                                   nullptr, out_part, 1024, 1024,
                                                   nullptr, (size_t)2048 * 1024);
    redout_k<<<2048, 256, 0, stream>>>(out_part, d_out, xraw);
}

// Round 6
// 261.387 us; speedup vs baseline: 1.4939x; 1.0447x over previous
//
#include <hip/hip_runtime.h>
#include <stdint.h>

typedef uint16_t u16;
typedef u16   u16x4  __attribute__((ext_vector_type(4)));
typedef u16   u16x8  __attribute__((ext_vector_type(8)));
typedef __bf16 bf16x8 __attribute__((ext_vector_type(8)));
typedef float f32x4  __attribute__((ext_vector_type(4)));

__device__ __forceinline__ float b2f(u16 x) {
    union { uint32_t u; float f; } c; c.u = ((uint32_t)x) << 16; return c.f;
}
__device__ __forceinline__ u16 f2b(float f) {
    union { float f; uint32_t u; } c; c.f = f;
    uint32_t r = c.u + 0x7FFFu + ((c.u >> 16) & 1u);
    return (u16)(r >> 16);
}
__device__ __forceinline__ float silu_f(float x) { return x / (1.f + __expf(-x)); }

__device__ __forceinline__ void gload16(const u16* g, u16* l) {
    __builtin_amdgcn_global_load_lds(
        (const __attribute__((address_space(1))) void*)(g),
        (__attribute__((address_space(3))) void*)(l), 16, 0, 0);
}

// per-block dtype flag: 1 = f32 inputs, 0 = bf16. Contains barriers; call first.
__device__ __forceinline__ int dtype_flag_block(const u16* __restrict__ xraw) {
    __shared__ int bad;
    if (threadIdx.x == 0) bad = 0;
    __syncthreads();
    float v = b2f(xraw[threadIdx.x]);
    if (!(fabsf(v) < 1000.f)) atomicAdd(&bad, 1);   // NaN-safe
    __syncthreads();
    return bad;
}

// ---------------- unified input canonicalization (14 segments) ----------------
struct CvtArgs {
    const void* s[14];
    u16* d[14];
    int cum[15];
    int total;
};
__global__ __launch_bounds__(256) void cvt_all_k(CvtArgs a, const u16* __restrict__ xraw)
{
    int flag = dtype_flag_block(xraw);
    int u4 = blockIdx.x * 256 + threadIdx.x;
    if (u4 >= a.total) return;
    int seg = 0;
    while (u4 >= a.cum[seg + 1]) seg++;
    int local = u4 - a.cum[seg];
    const void* s = a.s[seg];
    u16x4 o;
    if (s == nullptr) {
        o[0] = o[1] = o[2] = o[3] = 0;
    } else if (flag) {
        f32x4 vv = ((const f32x4*)s)[local];
        for (int e = 0; e < 4; e++) o[e] = f2b(vv[e]);
    } else {
        o = ((const u16x4*)s)[local];
    }
    *(u16x4*)(a.d[seg] + (size_t)local * 4) = o;
}

// ---------------- MFMA NT GEMM core: C[m,n] = sum_k A[m,k]*B[n,k] ----------------
// 128x128 tile, BK=64, 4 waves (2x2), 4x4 of 16x16x32 bf16, swizzled LDS slots.
// AF32: A staged synchronously from f32 (load->cvt->ds_write); else async bf16.
// EPI 0: bf16 store. 1: f32 softplus(acc+bias). 2: f32 partial at Cf+z*zslab.
// 3: atomicAdd f32. Kc multiple of 64.
template<int EPI, int AF32>
__device__ __forceinline__ void gemm_core(
    int bx, int by, int bz,
    const u16* __restrict__ Ab, const float* __restrict__ Af,
    const u16* __restrict__ B,
    int Kc, int lda, int ldb,
    u16* __restrict__ Cb, float* __restrict__ Cf, int ldc, int ncols,
    const u16* __restrict__ bias, size_t zslab)
{
    __shared__ __align__(16) u16 lA[128 * 64];
    __shared__ __align__(16) u16 lB[128 * 64];
    const int tid  = threadIdx.x;
    const int wave = tid >> 6, lane = tid & 63;
    const int quad = lane >> 4, l16 = lane & 15;
    const int wm = wave & 1, wn = wave >> 1;
    const int row0 = by * 128, col0 = bx * 128;
    const int kbeg = bz * Kc;

    f32x4 acc[4][4];
    const f32x4 zf = {0.f, 0.f, 0.f, 0.f};
    for (int i = 0; i < 4; i++) for (int j = 0; j < 4; j++) acc[i][j] = zf;

    // chunk c in [0,1024): 16B at lX[c*8]; row r=c>>3, slot s=c&7 holds
    // k-group q=(s-(r>>1))&7 (bank swizzle).
    const u16* Abp[4]; const float* Afp[4]; const u16* Bp[4];
    int lbase[4], lofsA[4];
    for (int t = 0; t < 4; t++) {
        int c = t * 256 + tid;
        int r = c >> 3, s = c & 7;
        int q = (s - (r >> 1)) & 7;
        if (AF32) Afp[t] = Af + (size_t)(row0 + r) * lda + q * 8 + kbeg;
        else      Abp[t] = Ab + (size_t)(row0 + r) * lda + q * 8 + kbeg;
        Bp[t] = B + (size_t)(col0 + r) * ldb + q * 8 + kbeg;
        lbase[t] = (t * 256 + wave * 64) * 8;   // wave-uniform (async)
        lofsA[t] = c * 8;                       // per-lane (sync)
    }

    for (int k0 = 0; k0 < Kc; k0 += 64) {
        if (AF32) {
            for (int t = 0; t < 4; t++) {
                const float* ap = Afp[t] + k0;
                f32x4 v0 = *(const f32x4*)ap;
                f32x4 v1 = *(const f32x4*)(ap + 4);
                u16x8 w;
                for (int e = 0; e < 4; e++) { w[e] = f2b(v0[e]); w[4 + e] = f2b(v1[e]); }
                *(u16x8*)&lA[lofsA[t]] = w;
            }
        } else {
            for (int t = 0; t < 4; t++) gload16(Abp[t] + k0, &lA[lbase[t]]);
        }
        for (int t = 0; t < 4; t++) gload16(Bp[t] + k0, &lB[lbase[t]]);
        __syncthreads();
        for (int half = 0; half < 2; half++) {
            bf16x8 af[4], bfr[4];
            for (int i = 0; i < 4; i++) {
                int r = wm * 64 + i * 16 + l16;
                int s = (half * 4 + quad + (r >> 1)) & 7;
                af[i] = *(const bf16x8*)&lA[r * 64 + s * 8];
            }
            for (int j = 0; j < 4; j++) {
                int r = wn * 64 + j * 16 + l16;
                int s = (half * 4 + quad + (r >> 1)) & 7;
                bfr[j] = *(const bf16x8*)&lB[r * 64 + s * 8];
            }
            for (int i = 0; i < 4; i++)
                for (int j = 0; j < 4; j++)
                    acc[i][j] = __builtin_amdgcn_mfma_f32_16x16x32_bf16(af[i], bfr[j], acc[i][j], 0, 0, 0);
        }
        __syncthreads();
    }

    float* dstf = (EPI == 2) ? (Cf + (size_t)bz * zslab) : Cf;
    for (int i = 0; i < 4; i++) {
        int mb = row0 + wm * 64 + i * 16 + quad * 4;
        for (int j = 0; j < 4; j++) {
            int n = col0 + wn * 64 + j * 16 + l16;
            if (n >= ncols) continue;
            if (EPI == 0) {
                for (int v = 0; v < 4; v++)
                    Cb[(size_t)(mb + v) * ldc + n] = f2b(acc[i][j][v]);
            } else if (EPI == 1) {
                float bv = b2f(bias[n]);
                for (int v = 0; v < 4; v++) {
                    float xx = acc[i][j][v] + bv;
                    dstf[(size_t)(mb + v) * ldc + n] =
                        fmaxf(xx, 0.f) + log1pf(__expf(-fabsf(xx)));
                }
            } else if (EPI == 2) {
                for (int v = 0; v < 4; v++)
                    dstf[(size_t)(mb + v) * ldc + n] = acc[i][j][v];
            } else {
                for (int v = 0; v < 4; v++)
                    atomicAdd(&dstf[(size_t)(mb + v) * ldc + n], acc[i][j][v]);
            }
        }
    }
}

template<int EPI, int AF32>
__global__ __launch_bounds__(256) void gemm_bt(
    const u16* __restrict__ Ab, const float* __restrict__ Af,
    const u16* __restrict__ B, int Kc, int lda, int ldb,
    u16* __restrict__ Cb, float* __restrict__ Cf, int ldc, int ncols,
    const u16* __restrict__ bias, size_t zslab)
{
    gemm_core<EPI, AF32>(blockIdx.x, blockIdx.y, blockIdx.z,
                         Ab, Af, B, Kc, lda, ldb, Cb, Cf, ldc, ncols, bias, zslab);
}

// ---------------- depthwise causal conv(4) + bias + SiLU ----------------
__global__ __launch_bounds__(256) void conv_silu_k(
    const u16* __restrict__ xr, const u16* __restrict__ cw,
    const u16* __restrict__ cb, u16* __restrict__ u)
{
    int tid = threadIdx.x;
    int bl  = blockIdx.x;       // b*1024 + l
    int l   = bl & 1023;
    int d0  = tid * 8;
    float acc[8];
    u16x8 bias = *(const u16x8*)&cb[d0];
    for (int j = 0; j < 8; j++) acc[j] = b2f(bias[j]);
    union { u16x8 v[4]; u16 s[32]; } wb;
    for (int t = 0; t < 4; t++) wb.v[t] = *(const u16x8*)&cw[d0 * 4 + t * 8];
    for (int t = 0; t < 4; t++) {
        int ls = l - 3 + t;
        if (ls < 0) continue;
        u16x8 xv = *(const u16x8*)&xr[(size_t)(bl - 3 + t) * 4096 + d0];
        for (int j = 0; j < 8; j++) acc[j] += b2f(xv[j]) * b2f(wb.s[j * 4 + t]);
    }
    u16x8 o;
    for (int j = 0; j < 8; j++) o[j] = f2b(silu_f(acc[j]));
    *(u16x8*)&u[(size_t)bl * 2048 + d0] = o;
}

// ---------------- fused: selective scan (blocks 0..511) + qkv (512..1007) ----------------
__global__ __launch_bounds__(256) void scan_qkv_k(
    const float* __restrict__ delta, const u16* __restrict__ u,
    const u16* __restrict__ xr, const float* __restrict__ xf,
    const u16* __restrict__ latent, const u16* __restrict__ Alog,
    const u16* __restrict__ Dp, u16* __restrict__ yg,
    const u16* __restrict__ Wc, u16* __restrict__ q, u16* __restrict__ k,
    u16* __restrict__ v)
{
    __shared__ float sm[1024];
    int tid = threadIdx.x;
    int bid = blockIdx.x;
    if (bid < 512) {
        float (*Bs)[16] = (float(*)[16])sm;
        float (*Cs)[16] = (float(*)[16])(sm + 512);
        int dblk = bid & 7, bg = bid >> 3;       // bg = b*32+g
        int d = dblk * 256 + tid;
        for (int idx = tid; idx < 512; idx += 256) {
            int p = idx >> 4, n = idx & 15;
            const float* xp = &xf[(size_t)(bg * 32 + p) * 128];
            Bs[p][n] = xp[64 + n];
            Cs[p][n] = xp[80 + n];
        }
        __syncthreads();
        float a[16], h[16];
        {
            u16x8 a0 = *(const u16x8*)&Alog[(size_t)d * 16];
            u16x8 a1 = *(const u16x8*)&Alog[(size_t)d * 16 + 8];
            u16x8 l0 = *(const u16x8*)&latent[((size_t)bg * 2048 + d) * 16];
            u16x8 l1 = *(const u16x8*)&latent[((size_t)bg * 2048 + d) * 16 + 8];
            for (int n = 0; n < 8; n++) {
                a[n] = -__expf(b2f(a0[n])); a[8 + n] = -__expf(b2f(a1[n]));
                h[n] = b2f(l0[n]);          h[8 + n] = b2f(l1[n]);
            }
        }
        float Dd = b2f(Dp[d]);
        for (int p = 0; p < 32; p++) {
            size_t row = (size_t)bg * 32 + p;
            float dlt = delta[row * 2048 + d];
            float uu  = b2f(u[row * 2048 + d]);
            float db  = dlt * uu;
            float y = 0.f;
            if (p == 0) {
                for (int n = 0; n < 16; n++) { h[n] += db * Bs[0][n]; y += h[n] * Cs[0][n]; }
            } else {
                for (int n = 0; n < 16; n++) {
                    float w = __expf(dlt * a[n]);
                    h[n] = w * h[n] + db * Bs[p][n];
                    y += h[n] * Cs[p][n];
                }
            }
            float rs = b2f(xr[row * 4096 + 2048 + d]);
            yg[row * 2048 + d] = f2b((y + uu * Dd) * silu_f(rs));
        }
    } else {
        float (*Ws)[16] = (float(*)[16])sm;
        for (int i = tid; i < 768; i += 256) Ws[i >> 4][i & 15] = b2f(Wc[i]);
        __syncthreads();
        int gid = (bid - 512) * 256 + tid;           // 126976 total
        int d = gid & 2047;
        int bi = gid >> 11;                          // b*31+i
        int b = bi / 31, i = bi - b * 31;
        const u16* lp = &latent[(((size_t)b * 32 + i) * 2048 + d) * 16];
        float lv[16];
        {
            u16x8 l0 = *(const u16x8*)lp, l1 = *(const u16x8*)(lp + 8);
            for (int m = 0; m < 8; m++) { lv[m] = b2f(l0[m]); lv[8 + m] = b2f(l1[m]); }
        }
        u16* outs[3] = {q, k, v};
        for (int pl = 0; pl < 3; pl++) {
            u16x8 o0, o1;
            for (int n = 0; n < 16; n++) {
                float s = 0.f;
                for (int m = 0; m < 16; m++) s += lv[m] * Ws[pl * 16 + n][m];
                if (n < 8) o0[n] = f2b(s); else o1[n - 8] = f2b(s);
            }
            u16* op = outs[pl] + (size_t)bi * 32768 + d * 16;
            *(u16x8*)op = o0; *(u16x8*)(op + 8) = o1;
        }
    }
}

// ---------------- fused: out-GEMM split-K (blocks 0..511) + scores (512..2433) ----------------
__global__ __launch_bounds__(256) void gemm_scores_k(
    const u16* __restrict__ yg, const u16* __restrict__ Wout, float* __restrict__ out_part,
    const u16* __restrict__ q, const u16* __restrict__ kk, float* __restrict__ sc)
{
    int bid = blockIdx.x;
    if (bid < 512) {
        int bx = bid & 7, by = (bid >> 3) & 15, bz = bid >> 7;
        gemm_core<2, 0>(bx, by, bz, yg, nullptr, Wout, 512, 2048, 2048,
                        nullptr, out_part, 1024, 1024, nullptr, (size_t)2048 * 1024);
        return;
    }
    int idx = bid - 512;             // b*961 + i*31 + j
    int b = idx / 961, r = idx - b * 961;
    int i = r / 31, j = r - i * 31;
    if (j > i) return;
    const u16* qp = q + ((size_t)b * 31 + i) * 32768;
    const u16* kp = kk + ((size_t)b * 31 + j) * 32768;
    float s = 0.f;
    for (int t = threadIdx.x * 8; t < 32768; t += 2048) {
        u16x8 a = *(const u16x8*)&qp[t];
        u16x8 c = *(const u16x8*)&kp[t];
        for (int e = 0; e < 8; e++) s += b2f(a[e]) * b2f(c[e]);
    }
    for (int off = 32; off; off >>= 1) s += __shfl_xor(s, off);
    __shared__ float red[4];
    if ((threadIdx.x & 63) == 0) red[threadIdx.x >> 6] = s;
    __syncthreads();
    if (threadIdx.x == 0)
        sc[idx] = (red[0] + red[1] + red[2] + red[3]) * 5.5242717e-3f; // 1/sqrt(32768)
}

// ---------------- fused epilogue: attv+softmax (blocks 0..1023) + redout (1024..3071) ----------------
__global__ __launch_bounds__(256) void attv_redout_k(
    const float* __restrict__ sc, const u16* __restrict__ v,
    const float* __restrict__ part, void* __restrict__ dout,
    const u16* __restrict__ xraw)
{
    int flag = dtype_flag_block(xraw);
    int bid = blockIdx.x;
    if (bid < 1024) {
        int chunk = bid & 15, bi = bid >> 4;
        int b = bi >> 5, i = (bi & 31) - 1;   // i = -1 -> zero row (group 0)
        __shared__ float as[32];
        if (i >= 0 && threadIdx.x < 64) {
            float x = (threadIdx.x <= i) ? sc[(size_t)b * 961 + i * 31 + threadIdx.x] : -3.4e38f;
            float mx = x;
            for (int off = 32; off; off >>= 1) mx = fmaxf(mx, __shfl_xor(mx, off));
            float e = (threadIdx.x <= i) ? __expf(x - mx) : 0.f;
            float sm = e;
            for (int off = 32; off; off >>= 1) sm += __shfl_xor(sm, off);
            if (threadIdx.x < 32) as[threadIdx.x] = e / sm;
        }
        __syncthreads();
        int dn = chunk * 2048 + threadIdx.x * 8;
        float acc[8] = {0, 0, 0, 0, 0, 0, 0, 0};
        if (i >= 0) {
            for (int j = 0; j <= i; j++) {
                u16x8 vv = *(const u16x8*)&v[((size_t)b * 31 + j) * 32768 + dn];
                float aj = as[j];
                for (int e = 0; e < 8; e++) acc[e] += aj * b2f(vv[e]);
            }
            for (int e = 0; e < 8; e++) if (!(fabsf(acc[e]) < 1e30f)) acc[e] = 0.f;
        }
        size_t ofs = 2097152 + ((size_t)b * 32 + (i + 1)) * 32768 + dn;
        if (flag) {
            f32x4 o0, o1;
            for (int e = 0; e < 4; e++) { o0[e] = acc[e]; o1[e] = acc[4 + e]; }
            *(f32x4*)((float*)dout + ofs) = o0;
            *(f32x4*)((float*)dout + ofs + 4) = o1;
        } else {
            u16x8 o;
            for (int e = 0; e < 8; e++) o[e] = f2b(acc[e]);
            *(u16x8*)((u16*)dout + ofs) = o;
        }
    } else {
        int gid = (bid - 1024) * 256 + threadIdx.x;   // 524288 total
        int m = gid >> 8;
        int j = (gid & 255) * 4;
        f32x4 s = {0.f, 0.f, 0.f, 0.f};
        for (int ks = 0; ks < 4; ks++) {
            f32x4 p = *(const f32x4*)&part[((size_t)ks * 2048 + m) * 1024 + j];
            for (int e = 0; e < 4; e++) s[e] += p[e];
        }
        for (int e = 0; e < 4; e++) if (!(fabsf(s[e]) < 1e30f)) s[e] = 0.f;
        if (flag) {
            ((f32x4*)dout)[(size_t)m * 256 + (j >> 2)] = s;
        } else {
            u16x4 o;
            for (int e = 0; e < 4; e++) o[e] = f2b(s[e]);
            ((u16x4*)dout)[(size_t)m * 256 + (j >> 2)] = o;
        }
    }
}

extern "C" void kernel_launch(void* const* d_in, const int* in_sizes, int n_in,
                              void* d_out, int out_size, void* d_ws, size_t ws_size,
                              hipStream_t stream)
{
    char* ws = (char*)d_ws;
    const u16* xraw = (const u16*)d_in[0];
    // canonical bf16 inputs
    u16* cx    = (u16*)(ws + 0);
    u16* clat  = (u16*)(ws + 4194304);
    u16* cWin  = (u16*)(ws + 8388608);
    u16* ccw   = (u16*)(ws + 16777216);
    u16* ccb   = (u16*)(ws + 16793600);
    u16* wxp   = (u16*)(ws + 16797696);   // 128x2048 (W_x + zero pad)
    u16* cWdt  = (u16*)(ws + 17321984);
    u16* cbdt  = (u16*)(ws + 17584128);
    u16* cWout = (u16*)(ws + 17588224);
    u16* cAlog = (u16*)(ws + 21782528);
    u16* cD    = (u16*)(ws + 21848064);
    u16* cWc   = (u16*)(ws + 21852160);
    // intermediates (private; ws ~268 MB)
    float* xdbl_f32 = (float*)(ws + 21853760);  // 2048x128 f32 (zeroed in cvt)
    float* sc       = (float*)(ws + 22902336);  // 1922 f32
    u16*   u        = (u16*)(ws + 22910080);    // 2048x2048 bf16
    u16*   xr       = (u16*)(ws + 31298688);    // 2048x4096 bf16
    u16*   yg       = (u16*)(ws + 48075904);    // 2048x2048 bf16
    float* delta    = (float*)(ws + 56464512);  // 2048x2048 f32
    u16*   qb       = (u16*)(ws + 73241728);    // 3x 2031616 bf16
    u16*   kb       = qb + 2031616;
    u16*   vb       = kb + 2031616;
    float* out_part = (float*)(ws + 85431424);  // 4x2048x1024 f32 (ends ~119 MB)

    // 1) canonicalize inputs to bf16 + zero xdbl_f32 accumulator
    CvtArgs ca;
    const void* srcs[14] = { d_in[0], d_in[1], d_in[2], d_in[3], d_in[4],
                             d_in[5], nullptr, d_in[6], d_in[7], d_in[8],
                             d_in[9], d_in[10], d_in[11], nullptr };
    u16* dsts[14] = { cx, clat, cWin, ccw, ccb,
                      wxp, wxp + 196608, cWdt, cbdt, cWout,
                      cAlog, cD, cWc, (u16*)xdbl_f32 };
    int ns[14] = { 2097152, 2097152, 4194304, 8192, 2048,
                   196608, 65536, 131072, 2048, 2097152,
                   32768, 2048, 768, 524288 };
    int cum = 0;
    for (int i = 0; i < 14; i++) {
        ca.s[i] = srcs[i]; ca.d[i] = dsts[i];
        ca.cum[i] = cum; cum += ns[i] / 4;
    }
    ca.cum[14] = cum; ca.total = cum;    // 2,862,784 units
    cvt_all_k<<<(cum + 255) / 256, 256, 0, stream>>>(ca, xraw);

    // 2) xr = x @ W_in^T (M=2048,N=4096,K=1024)
    gemm_bt<0, 0><<<dim3(32, 16, 1), 256, 0, stream>>>(cx, nullptr, cWin, 1024, 1024, 1024,
                                                       xr, nullptr, 4096, 4096, nullptr, 0);
    // 3) depthwise conv + SiLU
    conv_silu_k<<<2048, 256, 0, stream>>>(xr, ccw, ccb, u);
    // 4) x_dbl = u @ W_x^T, split-K 16, atomic f32 accumulate (M=2048,N=128,K=2048)
    gemm_bt<3, 0><<<dim3(1, 16, 16), 256, 0, stream>>>(u, nullptr, wxp, 128, 2048, 2048,
                                                       nullptr, xdbl_f32, 128, 128, nullptr, 0);
    // 5) delta = softplus(xdbl[:,:64] @ W_dt^T + b_dt), A staged from f32 (K=64)
    gemm_bt<1, 1><<<dim3(16, 16, 1), 256, 0, stream>>>(nullptr, xdbl_f32, cWdt, 64, 128, 64,
                                                       nullptr, delta, 2048, 2048, cbdt, 0);
    // 6) selective scan + gating (blocks 0..511) | qkv (512..1007)
    scan_qkv_k<<<1008, 256, 0, stream>>>(delta, u, xr, xdbl_f32, clat, cAlog, cD, yg,
                                         cWc, qb, kb, vb);
    // 7) out-GEMM split-K 4 (blocks 0..511) | scores (512..2433)
    gemm_scores_k<<<2434, 256, 0, stream>>>(yg, cWout, out_part, qb, kb, sc);
    // 8) attv+softmax -> d_out[2097152:] | split-K reduce -> d_out[0:2097152]
    attv_redout_k<<<3072, 256, 0, stream>>>(sc, vb, out_part, d_out, xraw);
}

// Round 7
// 257.580 us; speedup vs baseline: 1.5160x; 1.0148x over previous
//
#include <hip/hip_runtime.h>
#include <stdint.h>

typedef uint16_t u16;
typedef u16   u16x4  __attribute__((ext_vector_type(4)));
typedef u16   u16x8  __attribute__((ext_vector_type(8)));
typedef __bf16 bf16x8 __attribute__((ext_vector_type(8)));
typedef float f32x4  __attribute__((ext_vector_type(4)));

__device__ __forceinline__ float b2f(u16 x) {
    union { uint32_t u; float f; } c; c.u = ((uint32_t)x) << 16; return c.f;
}
__device__ __forceinline__ u16 f2b(float f) {
    union { float f; uint32_t u; } c; c.f = f;
    uint32_t r = c.u + 0x7FFFu + ((c.u >> 16) & 1u);
    return (u16)(r >> 16);
}
__device__ __forceinline__ float silu_f(float x) { return x / (1.f + __expf(-x)); }

__device__ __forceinline__ void gload16(const u16* g, u16* l) {
    __builtin_amdgcn_global_load_lds(
        (const __attribute__((address_space(1))) void*)(g),
        (__attribute__((address_space(3))) void*)(l), 16, 0, 0);
}

// per-block dtype flag: 1 = f32 inputs, 0 = bf16. Contains barriers; call first.
__device__ __forceinline__ int dtype_flag_block(const u16* __restrict__ xraw) {
    __shared__ int bad;
    if (threadIdx.x == 0) bad = 0;
    __syncthreads();
    float v = b2f(xraw[threadIdx.x]);
    if (!(fabsf(v) < 1000.f)) atomicAdd(&bad, 1);   // NaN-safe
    __syncthreads();
    return bad;
}

// ---------------- unified input canonicalization (13 segments) ----------------
struct CvtArgs {
    const void* s[13];
    u16* d[13];
    int cum[14];
    int total;
};
__global__ __launch_bounds__(256) void cvt_all_k(CvtArgs a, const u16* __restrict__ xraw)
{
    int flag = dtype_flag_block(xraw);
    int u4 = blockIdx.x * 256 + threadIdx.x;
    if (u4 >= a.total) return;
    int seg = 0;
    while (u4 >= a.cum[seg + 1]) seg++;
    int local = u4 - a.cum[seg];
    const void* s = a.s[seg];
    u16x4 o;
    if (s == nullptr) {
        o[0] = o[1] = o[2] = o[3] = 0;
    } else if (flag) {
        f32x4 vv = ((const f32x4*)s)[local];
        for (int e = 0; e < 4; e++) o[e] = f2b(vv[e]);
    } else {
        o = ((const u16x4*)s)[local];
    }
    *(u16x4*)(a.d[seg] + (size_t)local * 4) = o;
}

// ---------------- MFMA NT GEMM core: C[m,n] = sum_k A[m,k]*B[n,k] ----------------
// 128(M) x TN(N) tile, BK=64, 4 waves (2x2), swizzled LDS slots.
// TN=128: 4x4 subtiles/wave; TN=64: 4x2 (grid 2x denser -> 4 blocks/CU).
// AMODE 0: async bf16 A. AMODE 2: A = sum of 16 f32 slabs (stride 262144),
// staged sync (load->sum->cvt->ds_write). EPI 0: bf16 store. 1: f32
// softplus(acc+bias). 2: f32 partial at Cf + z*zslab. Kc multiple of 64.
template<int EPI, int AMODE, int TN>
__device__ __forceinline__ void gemm_core(
    int bx, int by, int bz,
    const u16* __restrict__ Ab, const float* __restrict__ Af,
    const u16* __restrict__ B,
    int Kc, int lda, int ldb,
    u16* __restrict__ Cb, float* __restrict__ Cf, int ldc, int ncols,
    const u16* __restrict__ bias, size_t zslab)
{
    constexpr int NJ = TN / 32;       // B subtiles per wave (cols/16/2waves)
    constexpr int BT = TN / 32;       // B staging iterations
    __shared__ __align__(16) u16 lA[128 * 64];
    __shared__ __align__(16) u16 lB[TN * 64];
    const int tid  = threadIdx.x;
    const int wave = tid >> 6, lane = tid & 63;
    const int quad = lane >> 4, l16 = lane & 15;
    const int wm = wave & 1, wn = wave >> 1;
    const int row0 = by * 128, col0 = bx * TN;
    const int kbeg = bz * Kc;

    f32x4 acc[4][NJ];
    const f32x4 zf = {0.f, 0.f, 0.f, 0.f};
    for (int i = 0; i < 4; i++) for (int j = 0; j < NJ; j++) acc[i][j] = zf;

    // chunk c: 16B at lX[c*8]; row r=c>>3, slot s=c&7 holds k-group
    // q=(s-(r>>1))&7 (bank swizzle).
    const u16* Abp[4]; const float* Afp[4]; const u16* Bp[BT];
    int lbaseA[4], lofsA[4], lbaseB[BT];
    for (int t = 0; t < 4; t++) {
        int c = t * 256 + tid;
        int r = c >> 3, s = c & 7;
        int q = (s - (r >> 1)) & 7;
        if (AMODE == 2) Afp[t] = Af + (size_t)(row0 + r) * lda + q * 8 + kbeg;
        else            Abp[t] = Ab + (size_t)(row0 + r) * lda + q * 8 + kbeg;
        lbaseA[t] = (t * 256 + wave * 64) * 8;
        lofsA[t] = c * 8;
    }
    for (int t = 0; t < BT; t++) {
        int c = t * 256 + tid;
        int r = c >> 3, s = c & 7;
        int q = (s - (r >> 1)) & 7;
        Bp[t] = B + (size_t)(col0 + r) * ldb + q * 8 + kbeg;
        lbaseB[t] = (t * 256 + wave * 64) * 8;
    }

    for (int k0 = 0; k0 < Kc; k0 += 64) {
        if (AMODE == 2) {
            for (int t = 0; t < 4; t++) {
                const float* ap = Afp[t] + k0;
                float v[8];
                for (int e = 0; e < 8; e++) v[e] = 0.f;
                for (int s = 0; s < 16; s++) {
                    f32x4 v0 = *(const f32x4*)(ap + (size_t)s * 262144);
                    f32x4 v1 = *(const f32x4*)(ap + (size_t)s * 262144 + 4);
                    for (int e = 0; e < 4; e++) { v[e] += v0[e]; v[4 + e] += v1[e]; }
                }
                u16x8 w;
                for (int e = 0; e < 8; e++) w[e] = f2b(v[e]);
                *(u16x8*)&lA[lofsA[t]] = w;
            }
        } else {
            for (int t = 0; t < 4; t++) gload16(Abp[t] + k0, &lA[lbaseA[t]]);
        }
        for (int t = 0; t < BT; t++) gload16(Bp[t] + k0, &lB[lbaseB[t]]);
        __syncthreads();
        for (int half = 0; half < 2; half++) {
            bf16x8 af[4], bfr[NJ];
            for (int i = 0; i < 4; i++) {
                int r = wm * 64 + i * 16 + l16;
                int s = (half * 4 + quad + (r >> 1)) & 7;
                af[i] = *(const bf16x8*)&lA[r * 64 + s * 8];
            }
            for (int j = 0; j < NJ; j++) {
                int r = wn * (TN / 2) + j * 16 + l16;
                int s = (half * 4 + quad + (r >> 1)) & 7;
                bfr[j] = *(const bf16x8*)&lB[r * 64 + s * 8];
            }
            for (int i = 0; i < 4; i++)
                for (int j = 0; j < NJ; j++)
                    acc[i][j] = __builtin_amdgcn_mfma_f32_16x16x32_bf16(af[i], bfr[j], acc[i][j], 0, 0, 0);
        }
        __syncthreads();
    }

    float* dstf = (EPI == 2) ? (Cf + (size_t)bz * zslab) : Cf;
    for (int i = 0; i < 4; i++) {
        int mb = row0 + wm * 64 + i * 16 + quad * 4;
        for (int j = 0; j < NJ; j++) {
            int n = col0 + wn * (TN / 2) + j * 16 + l16;
            if (n >= ncols) continue;
            if (EPI == 0) {
                for (int v = 0; v < 4; v++)
                    Cb[(size_t)(mb + v) * ldc + n] = f2b(acc[i][j][v]);
            } else if (EPI == 1) {
                float bv = b2f(bias[n]);
                for (int v = 0; v < 4; v++) {
                    float xx = acc[i][j][v] + bv;
                    dstf[(size_t)(mb + v) * ldc + n] =
                        fmaxf(xx, 0.f) + log1pf(__expf(-fabsf(xx)));
                }
            } else {
                for (int v = 0; v < 4; v++)
                    dstf[(size_t)(mb + v) * ldc + n] = acc[i][j][v];
            }
        }
    }
}

template<int EPI, int AMODE, int TN>
__global__ __launch_bounds__(256) void gemm_bt(
    const u16* __restrict__ Ab, const float* __restrict__ Af,
    const u16* __restrict__ B, int Kc, int lda, int ldb,
    u16* __restrict__ Cb, float* __restrict__ Cf, int ldc, int ncols,
    const u16* __restrict__ bias, size_t zslab)
{
    gemm_core<EPI, AMODE, TN>(blockIdx.x, blockIdx.y, blockIdx.z,
                              Ab, Af, B, Kc, lda, ldb, Cb, Cf, ldc, ncols, bias, zslab);
}

// ---------------- depthwise causal conv(4) + bias + SiLU ----------------
__global__ __launch_bounds__(256) void conv_silu_k(
    const u16* __restrict__ xr, const u16* __restrict__ cw,
    const u16* __restrict__ cb, u16* __restrict__ u)
{
    int tid = threadIdx.x;
    int bl  = blockIdx.x;       // b*1024 + l
    int l   = bl & 1023;
    int d0  = tid * 8;
    float acc[8];
    u16x8 bias = *(const u16x8*)&cb[d0];
    for (int j = 0; j < 8; j++) acc[j] = b2f(bias[j]);
    union { u16x8 v[4]; u16 s[32]; } wb;
    for (int t = 0; t < 4; t++) wb.v[t] = *(const u16x8*)&cw[d0 * 4 + t * 8];
    for (int t = 0; t < 4; t++) {
        int ls = l - 3 + t;
        if (ls < 0) continue;
        u16x8 xv = *(const u16x8*)&xr[(size_t)(bl - 3 + t) * 4096 + d0];
        for (int j = 0; j < 8; j++) acc[j] += b2f(xv[j]) * b2f(wb.s[j * 4 + t]);
    }
    u16x8 o;
    for (int j = 0; j < 8; j++) o[j] = f2b(silu_f(acc[j]));
    *(u16x8*)&u[(size_t)bl * 2048 + d0] = o;
}

// ---------------- fused: selective scan (blocks 0..511) + qkv (512..1007) ----------------
// B/C rows come from the 16 xdbl split-K slabs, summed inline.
__global__ __launch_bounds__(256) void scan_qkv_k(
    const float* __restrict__ delta, const u16* __restrict__ u,
    const u16* __restrict__ xr, const float* __restrict__ xpart,
    const u16* __restrict__ latent, const u16* __restrict__ Alog,
    const u16* __restrict__ Dp, u16* __restrict__ yg,
    const u16* __restrict__ Wc, u16* __restrict__ q, u16* __restrict__ k,
    u16* __restrict__ v)
{
    __shared__ float sm[1024];
    int tid = threadIdx.x;
    int bid = blockIdx.x;
    if (bid < 512) {
        float (*Bs)[16] = (float(*)[16])sm;
        float (*Cs)[16] = (float(*)[16])(sm + 512);
        int dblk = bid & 7, bg = bid >> 3;       // bg = b*32+g
        int d = dblk * 256 + tid;
        for (int idx = tid; idx < 1024; idx += 256) {
            int p = (idx >> 4) & 31, n = idx & 15;
            int which = idx >> 9;                // 0 -> B (col 64+n), 1 -> C (col 80+n)
            const float* xp = &xpart[(size_t)(bg * 32 + p) * 128 + 64 + which * 16 + n];
            float s = 0.f;
            for (int sl = 0; sl < 16; sl++) s += xp[(size_t)sl * 262144];
            if (which == 0) Bs[p][n] = s; else Cs[p][n] = s;
        }
        __syncthreads();
        float a[16], h[16];
        {
            u16x8 a0 = *(const u16x8*)&Alog[(size_t)d * 16];
            u16x8 a1 = *(const u16x8*)&Alog[(size_t)d * 16 + 8];
            u16x8 l0 = *(const u16x8*)&latent[((size_t)bg * 2048 + d) * 16];
            u16x8 l1 = *(const u16x8*)&latent[((size_t)bg * 2048 + d) * 16 + 8];
            for (int n = 0; n < 8; n++) {
                a[n] = -__expf(b2f(a0[n])); a[8 + n] = -__expf(b2f(a1[n]));
                h[n] = b2f(l0[n]);          h[8 + n] = b2f(l1[n]);
            }
        }
        float Dd = b2f(Dp[d]);
        for (int p = 0; p < 32; p++) {
            size_t row = (size_t)bg * 32 + p;
            float dlt = delta[row * 2048 + d];
            float uu  = b2f(u[row * 2048 + d]);
            float db  = dlt * uu;
            float y = 0.f;
            if (p == 0) {
                for (int n = 0; n < 16; n++) { h[n] += db * Bs[0][n]; y += h[n] * Cs[0][n]; }
            } else {
                for (int n = 0; n < 16; n++) {
                    float w = __expf(dlt * a[n]);
                    h[n] = w * h[n] + db * Bs[p][n];
                    y += h[n] * Cs[p][n];
                }
            }
            float rs = b2f(xr[row * 4096 + 2048 + d]);
            yg[row * 2048 + d] = f2b((y + uu * Dd) * silu_f(rs));
        }
    } else {
        float (*Ws)[16] = (float(*)[16])sm;
        for (int i = tid; i < 768; i += 256) Ws[i >> 4][i & 15] = b2f(Wc[i]);
        __syncthreads();
        int gid = (bid - 512) * 256 + tid;           // 126976 total
        int d = gid & 2047;
        int bi = gid >> 11;                          // b*31+i
        int b = bi / 31, i = bi - b * 31;
        const u16* lp = &latent[(((size_t)b * 32 + i) * 2048 + d) * 16];
        float lv[16];
        {
            u16x8 l0 = *(const u16x8*)lp, l1 = *(const u16x8*)(lp + 8);
            for (int m = 0; m < 8; m++) { lv[m] = b2f(l0[m]); lv[8 + m] = b2f(l1[m]); }
        }
        u16* outs[3] = {q, k, v};
        for (int pl = 0; pl < 3; pl++) {
            u16x8 o0, o1;
            for (int n = 0; n < 16; n++) {
                float s = 0.f;
                for (int m = 0; m < 16; m++) s += lv[m] * Ws[pl * 16 + n][m];
                if (n < 8) o0[n] = f2b(s); else o1[n - 8] = f2b(s);
            }
            u16* op = outs[pl] + (size_t)bi * 32768 + d * 16;
            *(u16x8*)op = o0; *(u16x8*)(op + 8) = o1;
        }
    }
}

// ---------------- fused: out-GEMM 128x64 split-K2 (blocks 0..511) + scores (512..2433) ----------------
__global__ __launch_bounds__(256) void gemm_scores_k(
    const u16* __restrict__ yg, const u16* __restrict__ Wout, float* __restrict__ out_part,
    const u16* __restrict__ q, const u16* __restrict__ kk, float* __restrict__ sc)
{
    int bid = blockIdx.x;
    if (bid < 512) {
        int bx = bid & 15, by = (bid >> 4) & 15, bz = bid >> 8;
        gemm_core<2, 0, 64>(bx, by, bz, yg, nullptr, Wout, 1024, 2048, 2048,
                            nullptr, out_part, 1024, 1024, nullptr, (size_t)2048 * 1024);
        return;
    }
    int idx = bid - 512;             // b*961 + i*31 + j
    int b = idx / 961, r = idx - b * 961;
    int i = r / 31, j = r - i * 31;
    if (j > i) return;
    const u16* qp = q + ((size_t)b * 31 + i) * 32768;
    const u16* kp = kk + ((size_t)b * 31 + j) * 32768;
    float s = 0.f;
    for (int t = threadIdx.x * 8; t < 32768; t += 2048) {
        u16x8 a = *(const u16x8*)&qp[t];
        u16x8 c = *(const u16x8*)&kp[t];
        for (int e = 0; e < 8; e++) s += b2f(a[e]) * b2f(c[e]);
    }
    for (int off = 32; off; off >>= 1) s += __shfl_xor(s, off);
    __shared__ float red[4];
    if ((threadIdx.x & 63) == 0) red[threadIdx.x >> 6] = s;
    __syncthreads();
    if (threadIdx.x == 0)
        sc[idx] = (red[0] + red[1] + red[2] + red[3]) * 5.5242717e-3f; // 1/sqrt(32768)
}

// ---------------- fused epilogue: attv+softmax (0..1023) + redout KS=2 (1024..3071) ----------------
__global__ __launch_bounds__(256) void attv_redout_k(
    const float* __restrict__ sc, const u16* __restrict__ v,
    const float* __restrict__ part, void* __restrict__ dout,
    const u16* __restrict__ xraw)
{
    int flag = dtype_flag_block(xraw);
    int bid = blockIdx.x;
    if (bid < 1024) {
        int chunk = bid & 15, bi = bid >> 4;
        int b = bi >> 5, i = (bi & 31) - 1;   // i = -1 -> zero row (group 0)
        __shared__ float as[32];
        if (i >= 0 && threadIdx.x < 64) {
            float x = (threadIdx.x <= i) ? sc[(size_t)b * 961 + i * 31 + threadIdx.x] : -3.4e38f;
            float mx = x;
            for (int off = 32; off; off >>= 1) mx = fmaxf(mx, __shfl_xor(mx, off));
            float e = (threadIdx.x <= i) ? __expf(x - mx) : 0.f;
            float sm = e;
            for (int off = 32; off; off >>= 1) sm += __shfl_xor(sm, off);
            if (threadIdx.x < 32) as[threadIdx.x] = e / sm;
        }
        __syncthreads();
        int dn = chunk * 2048 + threadIdx.x * 8;
        float acc[8] = {0, 0, 0, 0, 0, 0, 0, 0};
        if (i >= 0) {
            for (int j = 0; j <= i; j++) {
                u16x8 vv = *(const u16x8*)&v[((size_t)b * 31 + j) * 32768 + dn];
                float aj = as[j];
                for (int e = 0; e < 8; e++) acc[e] += aj * b2f(vv[e]);
            }
            for (int e = 0; e < 8; e++) if (!(fabsf(acc[e]) < 1e30f)) acc[e] = 0.f;
        }
        size_t ofs = 2097152 + ((size_t)b * 32 + (i + 1)) * 32768 + dn;
        if (flag) {
            f32x4 o0, o1;
            for (int e = 0; e < 4; e++) { o0[e] = acc[e]; o1[e] = acc[4 + e]; }
            *(f32x4*)((float*)dout + ofs) = o0;
            *(f32x4*)((float*)dout + ofs + 4) = o1;
        } else {
            u16x8 o;
            for (int e = 0; e < 8; e++) o[e] = f2b(acc[e]);
            *(u16x8*)((u16*)dout + ofs) = o;
        }
    } else {
        int gid = (bid - 1024) * 256 + threadIdx.x;   // 524288 total
        int m = gid >> 8;
        int j = (gid & 255) * 4;
        f32x4 s = {0.f, 0.f, 0.f, 0.f};
        for (int ks = 0; ks < 2; ks++) {
            f32x4 p = *(const f32x4*)&part[((size_t)ks * 2048 + m) * 1024 + j];
            for (int e = 0; e < 4; e++) s[e] += p[e];
        }
        for (int e = 0; e < 4; e++) if (!(fabsf(s[e]) < 1e30f)) s[e] = 0.f;
        if (flag) {
            ((f32x4*)dout)[(size_t)m * 256 + (j >> 2)] = s;
        } else {
            u16x4 o;
            for (int e = 0; e < 4; e++) o[e] = f2b(s[e]);
            ((u16x4*)dout)[(size_t)m * 256 + (j >> 2)] = o;
        }
    }
}

extern "C" void kernel_launch(void* const* d_in, const int* in_sizes, int n_in,
                              void* d_out, int out_size, void* d_ws, size_t ws_size,
                              hipStream_t stream)
{
    char* ws = (char*)d_ws;
    const u16* xraw = (const u16*)d_in[0];
    // canonical bf16 inputs
    u16* cx    = (u16*)(ws + 0);
    u16* clat  = (u16*)(ws + 4194304);
    u16* cWin  = (u16*)(ws + 8388608);
    u16* ccw   = (u16*)(ws + 16777216);
    u16* ccb   = (u16*)(ws + 16793600);
    u16* wxp   = (u16*)(ws + 16797696);   // 128x2048 (W_x + zero pad)
    u16* cWdt  = (u16*)(ws + 17321984);
    u16* cbdt  = (u16*)(ws + 17584128);
    u16* cWout = (u16*)(ws + 17588224);
    u16* cAlog = (u16*)(ws + 21782528);
    u16* cD    = (u16*)(ws + 21848064);
    u16* cWc   = (u16*)(ws + 21852160);
    // intermediates (private; ws ~268 MB)
    float* xdbl_part = (float*)(ws + 21853760);  // 16 x 2048x128 f32 slabs
    float* sc        = (float*)(ws + 38630976);  // 1922 f32
    u16*   u         = (u16*)(ws + 38638720);    // 2048x2048 bf16
    u16*   xr        = (u16*)(ws + 47027328);    // 2048x4096 bf16
    u16*   yg        = (u16*)(ws + 63804544);    // 2048x2048 bf16
    float* delta     = (float*)(ws + 72193152);  // 2048x2048 f32
    u16*   qb        = (u16*)(ws + 88970368);    // 3x 2031616 bf16
    u16*   kb        = qb + 2031616;
    u16*   vb        = kb + 2031616;
    float* out_part  = (float*)(ws + 101160064); // 2x2048x1024 f32 (ends ~118 MB)

    // 1) canonicalize inputs to bf16
    CvtArgs ca;
    const void* srcs[13] = { d_in[0], d_in[1], d_in[2], d_in[3], d_in[4],
                             d_in[5], nullptr, d_in[6], d_in[7], d_in[8],
                             d_in[9], d_in[10], d_in[11] };
    u16* dsts[13] = { cx, clat, cWin, ccw, ccb,
                      wxp, wxp + 196608, cWdt, cbdt, cWout,
                      cAlog, cD, cWc };
    int ns[13] = { 2097152, 2097152, 4194304, 8192, 2048,
                   196608, 65536, 131072, 2048, 2097152,
                   32768, 2048, 768 };
    int cum = 0;
    for (int i = 0; i < 13; i++) {
        ca.s[i] = srcs[i]; ca.d[i] = dsts[i];
        ca.cum[i] = cum; cum += ns[i] / 4;
    }
    ca.cum[13] = cum; ca.total = cum;    // 2,731,712 units
    cvt_all_k<<<(cum + 255) / 256, 256, 0, stream>>>(ca, xraw);

    // 2) xr = x @ W_in^T (M=2048,N=4096,K=1024), 128x64 tiles -> 1024 blocks (4/CU)
    gemm_bt<0, 0, 64><<<dim3(64, 16, 1), 256, 0, stream>>>(cx, nullptr, cWin, 1024, 1024, 1024,
                                                           xr, nullptr, 4096, 4096, nullptr, 0);
    // 3) depthwise conv + SiLU
    conv_silu_k<<<2048, 256, 0, stream>>>(xr, ccw, ccb, u);
    // 4) x_dbl = u @ W_x^T, split-K 16 -> f32 partial slabs (M=2048,N=128,K=2048)
    gemm_bt<2, 0, 128><<<dim3(1, 16, 16), 256, 0, stream>>>(u, nullptr, wxp, 128, 2048, 2048,
                                                            nullptr, xdbl_part, 128, 128,
                                                            nullptr, 262144);
    // 5) delta = softplus(xdbl[:,:64] @ W_dt^T + b_dt); A = 16-slab sum (K=64)
    gemm_bt<1, 2, 128><<<dim3(16, 16, 1), 256, 0, stream>>>(nullptr, xdbl_part, cWdt, 64, 128, 64,
                                                            nullptr, delta, 2048, 2048, cbdt, 0);
    // 6) selective scan + gating (blocks 0..511) | qkv (512..1007)
    scan_qkv_k<<<1008, 256, 0, stream>>>(delta, u, xr, xdbl_part, clat, cAlog, cD, yg,
                                         cWc, qb, kb, vb);
    // 7) out-GEMM 128x64 split-K2 (blocks 0..511) | scores (512..2433)
    gemm_scores_k<<<2434, 256, 0, stream>>>(yg, cWout, out_part, qb, kb, sc);
    // 8) attv+softmax -> d_out[2097152:] | split-K reduce -> d_out[0:2097152]
    attv_redout_k<<<3072, 256, 0, stream>>>(sc, vb, out_part, d_out, xraw);
}

// Round 8
// 243.965 us; speedup vs baseline: 1.6006x; 1.0558x over previous
//
#include <hip/hip_runtime.h>
#include <stdint.h>

typedef uint16_t u16;
typedef u16   u16x4  __attribute__((ext_vector_type(4)));
typedef u16   u16x8  __attribute__((ext_vector_type(8)));
typedef __bf16 bf16x8 __attribute__((ext_vector_type(8)));
typedef float f32x4  __attribute__((ext_vector_type(4)));

__device__ __forceinline__ float b2f(u16 x) {
    union { uint32_t u; float f; } c; c.u = ((uint32_t)x) << 16; return c.f;
}
__device__ __forceinline__ u16 f2b(float f) {
    union { float f; uint32_t u; } c; c.f = f;
    uint32_t r = c.u + 0x7FFFu + ((c.u >> 16) & 1u);
    return (u16)(r >> 16);
}
__device__ __forceinline__ float silu_f(float x) { return x / (1.f + __expf(-x)); }

__device__ __forceinline__ void gload16(const u16* g, u16* l) {
    __builtin_amdgcn_global_load_lds(
        (const __attribute__((address_space(1))) void*)(g),
        (__attribute__((address_space(3))) void*)(l), 16, 0, 0);
}

// per-block dtype flag: 1 = f32 inputs, 0 = bf16. Contains barriers; call first.
__device__ __forceinline__ int dtype_flag_block(const u16* __restrict__ xraw) {
    __shared__ int bad;
    if (threadIdx.x == 0) bad = 0;
    __syncthreads();
    float v = b2f(xraw[threadIdx.x]);
    if (!(fabsf(v) < 1000.f)) atomicAdd(&bad, 1);   // NaN-safe
    __syncthreads();
    return bad;
}

// ---------------- unified input canonicalization (13 segments) ----------------
struct CvtArgs {
    const void* s[13];
    u16* d[13];
    int cum[14];
    int total;
};
__global__ __launch_bounds__(256) void cvt_all_k(CvtArgs a, const u16* __restrict__ xraw)
{
    int flag = dtype_flag_block(xraw);
    int u4 = blockIdx.x * 256 + threadIdx.x;
    if (u4 >= a.total) return;
    int seg = 0;
    while (u4 >= a.cum[seg + 1]) seg++;
    int local = u4 - a.cum[seg];
    const void* s = a.s[seg];
    u16x4 o;
    if (s == nullptr) {
        o[0] = o[1] = o[2] = o[3] = 0;
    } else if (flag) {
        f32x4 vv = ((const f32x4*)s)[local];
        for (int e = 0; e < 4; e++) o[e] = f2b(vv[e]);
    } else {
        o = ((const u16x4*)s)[local];
    }
    *(u16x4*)(a.d[seg] + (size_t)local * 4) = o;
}

// ---------------- MFMA NT GEMM core: C[m,n] = sum_k A[m,k]*B[n,k] ----------------
// 128(M) x TN(N) tile, BK=64, 4 waves (2x2), swizzled LDS slots.
// TN=128: 4x4 subtiles/wave; TN=64: 4x2. Async global_load_lds staging.
// EPI 0: bf16 store. 1: f32 softplus(acc+bias). 2: f32 partial at Cf+z*zslab.
// Kc multiple of 64.
template<int EPI, int TN>
__device__ __forceinline__ void gemm_core(
    int bx, int by, int bz,
    const u16* __restrict__ A, const u16* __restrict__ B,
    int Kc, int lda, int ldb,
    u16* __restrict__ Cb, float* __restrict__ Cf, int ldc, int ncols,
    const u16* __restrict__ bias, size_t zslab)
{
    constexpr int NJ = TN / 32;
    constexpr int BT = TN / 32;
    __shared__ __align__(16) u16 lA[128 * 64];
    __shared__ __align__(16) u16 lB[TN * 64];
    const int tid  = threadIdx.x;
    const int wave = tid >> 6, lane = tid & 63;
    const int quad = lane >> 4, l16 = lane & 15;
    const int wm = wave & 1, wn = wave >> 1;
    const int row0 = by * 128, col0 = bx * TN;
    const int kbeg = bz * Kc;

    f32x4 acc[4][NJ];
    const f32x4 zf = {0.f, 0.f, 0.f, 0.f};
    for (int i = 0; i < 4; i++) for (int j = 0; j < NJ; j++) acc[i][j] = zf;

    // chunk c: 16B at lX[c*8]; row r=c>>3, slot s=c&7 holds k-group
    // q=(s-(r>>1))&7 (bank swizzle).
    const u16* Ap[4]; const u16* Bp[BT];
    int lbaseA[4], lbaseB[BT];
    for (int t = 0; t < 4; t++) {
        int c = t * 256 + tid;
        int r = c >> 3, s = c & 7;
        int q = (s - (r >> 1)) & 7;
        Ap[t] = A + (size_t)(row0 + r) * lda + q * 8 + kbeg;
        lbaseA[t] = (t * 256 + wave * 64) * 8;
    }
    for (int t = 0; t < BT; t++) {
        int c = t * 256 + tid;
        int r = c >> 3, s = c & 7;
        int q = (s - (r >> 1)) & 7;
        Bp[t] = B + (size_t)(col0 + r) * ldb + q * 8 + kbeg;
        lbaseB[t] = (t * 256 + wave * 64) * 8;
    }

    for (int k0 = 0; k0 < Kc; k0 += 64) {
        for (int t = 0; t < 4; t++) gload16(Ap[t] + k0, &lA[lbaseA[t]]);
        for (int t = 0; t < BT; t++) gload16(Bp[t] + k0, &lB[lbaseB[t]]);
        __syncthreads();
        for (int half = 0; half < 2; half++) {
            bf16x8 af[4], bfr[NJ];
            for (int i = 0; i < 4; i++) {
                int r = wm * 64 + i * 16 + l16;
                int s = (half * 4 + quad + (r >> 1)) & 7;
                af[i] = *(const bf16x8*)&lA[r * 64 + s * 8];
            }
            for (int j = 0; j < NJ; j++) {
                int r = wn * (TN / 2) + j * 16 + l16;
                int s = (half * 4 + quad + (r >> 1)) & 7;
                bfr[j] = *(const bf16x8*)&lB[r * 64 + s * 8];
            }
            for (int i = 0; i < 4; i++)
                for (int j = 0; j < NJ; j++)
                    acc[i][j] = __builtin_amdgcn_mfma_f32_16x16x32_bf16(af[i], bfr[j], acc[i][j], 0, 0, 0);
        }
        __syncthreads();
    }

    float* dstf = (EPI == 2) ? (Cf + (size_t)bz * zslab) : Cf;
    for (int i = 0; i < 4; i++) {
        int mb = row0 + wm * 64 + i * 16 + quad * 4;
        for (int j = 0; j < NJ; j++) {
            int n = col0 + wn * (TN / 2) + j * 16 + l16;
            if (n >= ncols) continue;
            if (EPI == 0) {
                for (int v = 0; v < 4; v++)
                    Cb[(size_t)(mb + v) * ldc + n] = f2b(acc[i][j][v]);
            } else if (EPI == 1) {
                float bv = b2f(bias[n]);
                for (int v = 0; v < 4; v++) {
                    float xx = acc[i][j][v] + bv;
                    dstf[(size_t)(mb + v) * ldc + n] =
                        fmaxf(xx, 0.f) + log1pf(__expf(-fabsf(xx)));
                }
            } else {
                for (int v = 0; v < 4; v++)
                    dstf[(size_t)(mb + v) * ldc + n] = acc[i][j][v];
            }
        }
    }
}

template<int EPI, int TN>
__global__ __launch_bounds__(256) void gemm_bt(
    const u16* __restrict__ A, const u16* __restrict__ B,
    int Kc, int lda, int ldb,
    u16* __restrict__ Cb, float* __restrict__ Cf, int ldc, int ncols,
    const u16* __restrict__ bias, size_t zslab)
{
    gemm_core<EPI, TN>(blockIdx.x, blockIdx.y, blockIdx.z,
                       A, B, Kc, lda, ldb, Cb, Cf, ldc, ncols, bias, zslab);
}

// reduce 16 x_dbl split-K f32 slabs -> bf16 xdbl (2048 x 128)
__global__ __launch_bounds__(256) void redc_k(
    const float* __restrict__ part, u16* __restrict__ dst)
{
    int gid = blockIdx.x * 256 + threadIdx.x;   // 65536 total
    int idx = gid * 4;
    f32x4 s = {0.f, 0.f, 0.f, 0.f};
    for (int sl = 0; sl < 16; sl++) {
        f32x4 p = *(const f32x4*)&part[(size_t)sl * 262144 + idx];
        for (int e = 0; e < 4; e++) s[e] += p[e];
    }
    u16x4 o;
    for (int e = 0; e < 4; e++) o[e] = f2b(s[e]);
    *(u16x4*)&dst[idx] = o;
}

// ---------------- depthwise causal conv(4) + bias + SiLU ----------------
__global__ __launch_bounds__(256) void conv_silu_k(
    const u16* __restrict__ xr, const u16* __restrict__ cw,
    const u16* __restrict__ cb, u16* __restrict__ u)
{
    int tid = threadIdx.x;
    int bl  = blockIdx.x;       // b*1024 + l
    int l   = bl & 1023;
    int d0  = tid * 8;
    float acc[8];
    u16x8 bias = *(const u16x8*)&cb[d0];
    for (int j = 0; j < 8; j++) acc[j] = b2f(bias[j]);
    union { u16x8 v[4]; u16 s[32]; } wb;
    for (int t = 0; t < 4; t++) wb.v[t] = *(const u16x8*)&cw[d0 * 4 + t * 8];
    for (int t = 0; t < 4; t++) {
        int ls = l - 3 + t;
        if (ls < 0) continue;
        u16x8 xv = *(const u16x8*)&xr[(size_t)(bl - 3 + t) * 4096 + d0];
        for (int j = 0; j < 8; j++) acc[j] += b2f(xv[j]) * b2f(wb.s[j * 4 + t]);
    }
    u16x8 o;
    for (int j = 0; j < 8; j++) o[j] = f2b(silu_f(acc[j]));
    *(u16x8*)&u[(size_t)bl * 2048 + d0] = o;
}

// ---------------- fused: selective scan (blocks 0..511) + qkv (512..1007) ----------------
__global__ __launch_bounds__(256) void scan_qkv_k(
    const float* __restrict__ delta, const u16* __restrict__ u,
    const u16* __restrict__ xr, const u16* __restrict__ xdbl,
    const u16* __restrict__ latent, const u16* __restrict__ Alog,
    const u16* __restrict__ Dp, u16* __restrict__ yg,
    const u16* __restrict__ Wc, u16* __restrict__ q, u16* __restrict__ k,
    u16* __restrict__ v)
{
    __shared__ float sm[1024];
    int tid = threadIdx.x;
    int bid = blockIdx.x;
    if (bid < 512) {
        float (*Bs)[16] = (float(*)[16])sm;
        float (*Cs)[16] = (float(*)[16])(sm + 512);
        int dblk = bid & 7, bg = bid >> 3;       // bg = b*32+g
        int d = dblk * 256 + tid;
        for (int idx = tid; idx < 512; idx += 256) {
            int p = idx >> 4, n = idx & 15;
            const u16* xp = &xdbl[(size_t)(bg * 32 + p) * 128];
            Bs[p][n] = b2f(xp[64 + n]);
            Cs[p][n] = b2f(xp[80 + n]);
        }
        __syncthreads();
        float a[16], h[16];
        {
            u16x8 a0 = *(const u16x8*)&Alog[(size_t)d * 16];
            u16x8 a1 = *(const u16x8*)&Alog[(size_t)d * 16 + 8];
            u16x8 l0 = *(const u16x8*)&latent[((size_t)bg * 2048 + d) * 16];
            u16x8 l1 = *(const u16x8*)&latent[((size_t)bg * 2048 + d) * 16 + 8];
            for (int n = 0; n < 8; n++) {
                a[n] = -__expf(b2f(a0[n])); a[8 + n] = -__expf(b2f(a1[n]));
                h[n] = b2f(l0[n]);          h[8 + n] = b2f(l1[n]);
            }
        }
        float Dd = b2f(Dp[d]);
        for (int p = 0; p < 32; p++) {
            size_t row = (size_t)bg * 32 + p;
            float dlt = delta[row * 2048 + d];
            float uu  = b2f(u[row * 2048 + d]);
            float db  = dlt * uu;
            float y = 0.f;
            if (p == 0) {
                for (int n = 0; n < 16; n++) { h[n] += db * Bs[0][n]; y += h[n] * Cs[0][n]; }
            } else {
                for (int n = 0; n < 16; n++) {
                    float w = __expf(dlt * a[n]);
                    h[n] = w * h[n] + db * Bs[p][n];
                    y += h[n] * Cs[p][n];
                }
            }
            float rs = b2f(xr[row * 4096 + 2048 + d]);
            yg[row * 2048 + d] = f2b((y + uu * Dd) * silu_f(rs));
        }
    } else {
        float (*Ws)[16] = (float(*)[16])sm;
        for (int i = tid; i < 768; i += 256) Ws[i >> 4][i & 15] = b2f(Wc[i]);
        __syncthreads();
        int gid = (bid - 512) * 256 + tid;           // 126976 total
        int d = gid & 2047;
        int bi = gid >> 11;                          // b*31+i
        int b = bi / 31, i = bi - b * 31;
        const u16* lp = &latent[(((size_t)b * 32 + i) * 2048 + d) * 16];
        float lv[16];
        {
            u16x8 l0 = *(const u16x8*)lp, l1 = *(const u16x8*)(lp + 8);
            for (int m = 0; m < 8; m++) { lv[m] = b2f(l0[m]); lv[8 + m] = b2f(l1[m]); }
        }
        u16* outs[3] = {q, k, v};
        for (int pl = 0; pl < 3; pl++) {
            u16x8 o0, o1;
            for (int n = 0; n < 16; n++) {
                float s = 0.f;
                for (int m = 0; m < 16; m++) s += lv[m] * Ws[pl * 16 + n][m];
                if (n < 8) o0[n] = f2b(s); else o1[n - 8] = f2b(s);
            }
            u16* op = outs[pl] + (size_t)bi * 32768 + d * 16;
            *(u16x8*)op = o0; *(u16x8*)(op + 8) = o1;
        }
    }
}

// ---------------- fused: out-GEMM 128x64 split-K2 (blocks 0..511) + scores (512..2433) ----------------
__global__ __launch_bounds__(256) void gemm_scores_k(
    const u16* __restrict__ yg, const u16* __restrict__ Wout, float* __restrict__ out_part,
    const u16* __restrict__ q, const u16* __restrict__ kk, float* __restrict__ sc)
{
    int bid = blockIdx.x;
    if (bid < 512) {
        int bx = bid & 15, by = (bid >> 4) & 15, bz = bid >> 8;
        gemm_core<2, 64>(bx, by, bz, yg, Wout, 1024, 2048, 2048,
                         nullptr, out_part, 1024, 1024, nullptr, (size_t)2048 * 1024);
        return;
    }
    int idx = bid - 512;             // b*961 + i*31 + j
    int b = idx / 961, r = idx - b * 961;
    int i = r / 31, j = r - i * 31;
    if (j > i) return;
    const u16* qp = q + ((size_t)b * 31 + i) * 32768;
    const u16* kp = kk + ((size_t)b * 31 + j) * 32768;
    float s = 0.f;
    for (int t = threadIdx.x * 8; t < 32768; t += 2048) {
        u16x8 a = *(const u16x8*)&qp[t];
        u16x8 c = *(const u16x8*)&kp[t];
        for (int e = 0; e < 8; e++) s += b2f(a[e]) * b2f(c[e]);
    }
    for (int off = 32; off; off >>= 1) s += __shfl_xor(s, off);
    __shared__ float red[4];
    if ((threadIdx.x & 63) == 0) red[threadIdx.x >> 6] = s;
    __syncthreads();
    if (threadIdx.x == 0)
        sc[idx] = (red[0] + red[1] + red[2] + red[3]) * 5.5242717e-3f; // 1/sqrt(32768)
}

// ---------------- fused epilogue: attv+softmax (0..1023) + redout KS=2 (1024..3071) ----------------
__global__ __launch_bounds__(256) void attv_redout_k(
    const float* __restrict__ sc, const u16* __restrict__ v,
    const float* __restrict__ part, void* __restrict__ dout,
    const u16* __restrict__ xraw)
{
    int flag = dtype_flag_block(xraw);
    int bid = blockIdx.x;
    if (bid < 1024) {
        int chunk = bid & 15, bi = bid >> 4;
        int b = bi >> 5, i = (bi & 31) - 1;   // i = -1 -> zero row (group 0)
        __shared__ float as[32];
        if (i >= 0 && threadIdx.x < 64) {
            float x = (threadIdx.x <= i) ? sc[(size_t)b * 961 + i * 31 + threadIdx.x] : -3.4e38f;
            float mx = x;
            for (int off = 32; off; off >>= 1) mx = fmaxf(mx, __shfl_xor(mx, off));
            float e = (threadIdx.x <= i) ? __expf(x - mx) : 0.f;
            float sm = e;
            for (int off = 32; off; off >>= 1) sm += __shfl_xor(sm, off);
            if (threadIdx.x < 32) as[threadIdx.x] = e / sm;
        }
        __syncthreads();
        int dn = chunk * 2048 + threadIdx.x * 8;
        float acc[8] = {0, 0, 0, 0, 0, 0, 0, 0};
        if (i >= 0) {
            for (int j = 0; j <= i; j++) {
                u16x8 vv = *(const u16x8*)&v[((size_t)b * 31 + j) * 32768 + dn];
                float aj = as[j];
                for (int e = 0; e < 8; e++) acc[e] += aj * b2f(vv[e]);
            }
            for (int e = 0; e < 8; e++) if (!(fabsf(acc[e]) < 1e30f)) acc[e] = 0.f;
        }
        size_t ofs = 2097152 + ((size_t)b * 32 + (i + 1)) * 32768 + dn;
        if (flag) {
            f32x4 o0, o1;
            for (int e = 0; e < 4; e++) { o0[e] = acc[e]; o1[e] = acc[4 + e]; }
            *(f32x4*)((float*)dout + ofs) = o0;
            *(f32x4*)((float*)dout + ofs + 4) = o1;
        } else {
            u16x8 o;
            for (int e = 0; e < 8; e++) o[e] = f2b(acc[e]);
            *(u16x8*)((u16*)dout + ofs) = o;
        }
    } else {
        int gid = (bid - 1024) * 256 + threadIdx.x;   // 524288 total
        int m = gid >> 8;
        int j = (gid & 255) * 4;
        f32x4 s = {0.f, 0.f, 0.f, 0.f};
        for (int ks = 0; ks < 2; ks++) {
            f32x4 p = *(const f32x4*)&part[((size_t)ks * 2048 + m) * 1024 + j];
            for (int e = 0; e < 4; e++) s[e] += p[e];
        }
        for (int e = 0; e < 4; e++) if (!(fabsf(s[e]) < 1e30f)) s[e] = 0.f;
        if (flag) {
            ((f32x4*)dout)[(size_t)m * 256 + (j >> 2)] = s;
        } else {
            u16x4 o;
            for (int e = 0; e < 4; e++) o[e] = f2b(s[e]);
            ((u16x4*)dout)[(size_t)m * 256 + (j >> 2)] = o;
        }
    }
}

extern "C" void kernel_launch(void* const* d_in, const int* in_sizes, int n_in,
                              void* d_out, int out_size, void* d_ws, size_t ws_size,
                              hipStream_t stream)
{
    char* ws = (char*)d_ws;
    const u16* xraw = (const u16*)d_in[0];
    // canonical bf16 inputs
    u16* cx    = (u16*)(ws + 0);
    u16* clat  = (u16*)(ws + 4194304);
    u16* cWin  = (u16*)(ws + 8388608);
    u16* ccw   = (u16*)(ws + 16777216);
    u16* ccb   = (u16*)(ws + 16793600);
    u16* wxp   = (u16*)(ws + 16797696);   // 128x2048 (W_x + zero pad)
    u16* cWdt  = (u16*)(ws + 17321984);
    u16* cbdt  = (u16*)(ws + 17584128);
    u16* cWout = (u16*)(ws + 17588224);
    u16* cAlog = (u16*)(ws + 21782528);
    u16* cD    = (u16*)(ws + 21848064);
    u16* cWc   = (u16*)(ws + 21852160);
    // intermediates (private; ws ~268 MB)
    float* xdbl_part = (float*)(ws + 21853760);  // 16 x 2048x128 f32 slabs
    u16*   xdbl      = (u16*)(ws + 38630976);    // 2048x128 bf16 (reduced)
    float* sc        = (float*)(ws + 39155264);  // 1922 f32
    u16*   u         = (u16*)(ws + 39163008);    // 2048x2048 bf16
    u16*   xr        = (u16*)(ws + 47551616);    // 2048x4096 bf16
    u16*   yg        = (u16*)(ws + 64328832);    // 2048x2048 bf16
    float* delta     = (float*)(ws + 72717440);  // 2048x2048 f32
    u16*   qb        = (u16*)(ws + 89494656);    // 3x 2031616 bf16
    u16*   kb        = qb + 2031616;
    u16*   vb        = kb + 2031616;
    float* out_part  = (float*)(ws + 101684352); // 2x2048x1024 f32 (ends ~118 MB)

    // 1) canonicalize inputs to bf16
    CvtArgs ca;
    const void* srcs[13] = { d_in[0], d_in[1], d_in[2], d_in[3], d_in[4],
                             d_in[5], nullptr, d_in[6], d_in[7], d_in[8],
                             d_in[9], d_in[10], d_in[11] };
    u16* dsts[13] = { cx, clat, cWin, ccw, ccb,
                      wxp, wxp + 196608, cWdt, cbdt, cWout,
                      cAlog, cD, cWc };
    int ns[13] = { 2097152, 2097152, 4194304, 8192, 2048,
                   196608, 65536, 131072, 2048, 2097152,
                   32768, 2048, 768 };
    int cum = 0;
    for (int i = 0; i < 13; i++) {
        ca.s[i] = srcs[i]; ca.d[i] = dsts[i];
        ca.cum[i] = cum; cum += ns[i] / 4;
    }
    ca.cum[13] = cum; ca.total = cum;    // 2,731,712 units
    cvt_all_k<<<(cum + 255) / 256, 256, 0, stream>>>(ca, xraw);

    // 2) xr = x @ W_in^T (M=2048,N=4096,K=1024), 128x64 tiles -> 1024 blocks
    gemm_bt<0, 64><<<dim3(64, 16, 1), 256, 0, stream>>>(cx, cWin, 1024, 1024, 1024,
                                                        xr, nullptr, 4096, 4096, nullptr, 0);
    // 3) depthwise conv + SiLU
    conv_silu_k<<<2048, 256, 0, stream>>>(xr, ccw, ccb, u);
    // 4) x_dbl = u @ W_x^T, split-K 16 -> f32 partial slabs (M=2048,N=128,K=2048)
    gemm_bt<2, 128><<<dim3(1, 16, 16), 256, 0, stream>>>(u, wxp, 128, 2048, 2048,
                                                         nullptr, xdbl_part, 128, 128,
                                                         nullptr, 262144);
    // 5) reduce 16 slabs -> xdbl bf16 (2048x128)
    redc_k<<<256, 256, 0, stream>>>(xdbl_part, xdbl);
    // 6) delta = softplus(xdbl[:,:64] @ W_dt^T + b_dt), async bf16 A (K=64)
    gemm_bt<1, 128><<<dim3(16, 16, 1), 256, 0, stream>>>(xdbl, cWdt, 64, 128, 64,
                                                         nullptr, delta, 2048, 2048, cbdt, 0);
    // 7) selective scan + gating (blocks 0..511) | qkv (512..1007)
    scan_qkv_k<<<1008, 256, 0, stream>>>(delta, u, xr, xdbl, clat, cAlog, cD, yg,
                                         cWc, qb, kb, vb);
    // 8) out-GEMM 128x64 split-K2 (blocks 0..511) | scores (512..2433)
    gemm_scores_k<<<2434, 256, 0, stream>>>(yg, cWout, out_part, qb, kb, sc);
    // 9) attv+softmax -> d_out[2097152:] | split-K reduce -> d_out[0:2097152]
    attv_redout_k<<<3072, 256, 0, stream>>>(sc, vb, out_part, d_out, xraw);
}

// Round 9
// 226.490 us; speedup vs baseline: 1.7241x; 1.0772x over previous
//
#include <hip/hip_runtime.h>
#include <stdint.h>

typedef uint16_t u16;
typedef u16   u16x4  __attribute__((ext_vector_type(4)));
typedef u16   u16x8  __attribute__((ext_vector_type(8)));
typedef __bf16 bf16x8 __attribute__((ext_vector_type(8)));
typedef float f32x4  __attribute__((ext_vector_type(4)));

__device__ __forceinline__ float b2f(u16 x) {
    union { uint32_t u; float f; } c; c.u = ((uint32_t)x) << 16; return c.f;
}
__device__ __forceinline__ u16 f2b(float f) {
    union { float f; uint32_t u; } c; c.f = f;
    uint32_t r = c.u + 0x7FFFu + ((c.u >> 16) & 1u);
    return (u16)(r >> 16);
}
__device__ __forceinline__ float silu_f(float x) { return x / (1.f + __expf(-x)); }

__device__ __forceinline__ void gload16(const u16* g, u16* l) {
    __builtin_amdgcn_global_load_lds(
        (const __attribute__((address_space(1))) void*)(g),
        (__attribute__((address_space(3))) void*)(l), 16, 0, 0);
}

// per-block dtype flag: 1 = f32 inputs, 0 = bf16. Contains barriers; call first.
__device__ __forceinline__ int dtype_flag_block(const u16* __restrict__ xraw) {
    __shared__ int bad;
    if (threadIdx.x == 0) bad = 0;
    __syncthreads();
    float v = b2f(xraw[threadIdx.x]);
    if (!(fabsf(v) < 1000.f)) atomicAdd(&bad, 1);   // NaN-safe
    __syncthreads();
    return bad;
}

// ---------------- unified input canonicalization (13 segments) ----------------
struct CvtArgs {
    const void* s[13];
    u16* d[13];
    int cum[14];
    int total;
};
__global__ __launch_bounds__(256) void cvt_all_k(CvtArgs a, const u16* __restrict__ xraw)
{
    int flag = dtype_flag_block(xraw);
    int u4 = blockIdx.x * 256 + threadIdx.x;
    if (u4 >= a.total) return;
    int seg = 0;
    while (u4 >= a.cum[seg + 1]) seg++;
    int local = u4 - a.cum[seg];
    const void* s = a.s[seg];
    u16x4 o;
    if (s == nullptr) {
        o[0] = o[1] = o[2] = o[3] = 0;
    } else if (flag) {
        f32x4 vv = ((const f32x4*)s)[local];
        for (int e = 0; e < 4; e++) o[e] = f2b(vv[e]);
    } else {
        o = ((const u16x4*)s)[local];
    }
    *(u16x4*)(a.d[seg] + (size_t)local * 4) = o;
}

// ---------------- MFMA NT GEMM core: C[m,n] = sum_k A[m,k]*B[n,k] ----------------
// 128(M) x TN(N) tile, BK=64, 4 waves (2x2), swizzled LDS slots.
// TN=128: 4x4 subtiles/wave; TN=64: 4x2. Async global_load_lds staging.
// EPI 0: bf16 store. 1: f32 softplus(acc+bias). 2: f32 partial at Cf+z*zslab.
// Kc multiple of 64.
template<int EPI, int TN>
__device__ __forceinline__ void gemm_core(
    int bx, int by, int bz,
    const u16* __restrict__ A, const u16* __restrict__ B,
    int Kc, int lda, int ldb,
    u16* __restrict__ Cb, float* __restrict__ Cf, int ldc, int ncols,
    const u16* __restrict__ bias, size_t zslab)
{
    constexpr int NJ = TN / 32;
    constexpr int BT = TN / 32;
    __shared__ __align__(16) u16 lA[128 * 64];
    __shared__ __align__(16) u16 lB[TN * 64];
    const int tid  = threadIdx.x;
    const int wave = tid >> 6, lane = tid & 63;
    const int quad = lane >> 4, l16 = lane & 15;
    const int wm = wave & 1, wn = wave >> 1;
    const int row0 = by * 128, col0 = bx * TN;
    const int kbeg = bz * Kc;

    f32x4 acc[4][NJ];
    const f32x4 zf = {0.f, 0.f, 0.f, 0.f};
    for (int i = 0; i < 4; i++) for (int j = 0; j < NJ; j++) acc[i][j] = zf;

    // chunk c: 16B at lX[c*8]; row r=c>>3, slot s=c&7 holds k-group
    // q=(s-(r>>1))&7 (bank swizzle).
    const u16* Ap[4]; const u16* Bp[BT];
    int lbaseA[4], lbaseB[BT];
    for (int t = 0; t < 4; t++) {
        int c = t * 256 + tid;
        int r = c >> 3, s = c & 7;
        int q = (s - (r >> 1)) & 7;
        Ap[t] = A + (size_t)(row0 + r) * lda + q * 8 + kbeg;
        lbaseA[t] = (t * 256 + wave * 64) * 8;
    }
    for (int t = 0; t < BT; t++) {
        int c = t * 256 + tid;
        int r = c >> 3, s = c & 7;
        int q = (s - (r >> 1)) & 7;
        Bp[t] = B + (size_t)(col0 + r) * ldb + q * 8 + kbeg;
        lbaseB[t] = (t * 256 + wave * 64) * 8;
    }

    for (int k0 = 0; k0 < Kc; k0 += 64) {
        for (int t = 0; t < 4; t++) gload16(Ap[t] + k0, &lA[lbaseA[t]]);
        for (int t = 0; t < BT; t++) gload16(Bp[t] + k0, &lB[lbaseB[t]]);
        __syncthreads();
        for (int half = 0; half < 2; half++) {
            bf16x8 af[4], bfr[NJ];
            for (int i = 0; i < 4; i++) {
                int r = wm * 64 + i * 16 + l16;
                int s = (half * 4 + quad + (r >> 1)) & 7;
                af[i] = *(const bf16x8*)&lA[r * 64 + s * 8];
            }
            for (int j = 0; j < NJ; j++) {
                int r = wn * (TN / 2) + j * 16 + l16;
                int s = (half * 4 + quad + (r >> 1)) & 7;
                bfr[j] = *(const bf16x8*)&lB[r * 64 + s * 8];
            }
            for (int i = 0; i < 4; i++)
                for (int j = 0; j < NJ; j++)
                    acc[i][j] = __builtin_amdgcn_mfma_f32_16x16x32_bf16(af[i], bfr[j], acc[i][j], 0, 0, 0);
        }
        __syncthreads();
    }

    float* dstf = (EPI == 2) ? (Cf + (size_t)bz * zslab) : Cf;
    for (int i = 0; i < 4; i++) {
        int mb = row0 + wm * 64 + i * 16 + quad * 4;
        for (int j = 0; j < NJ; j++) {
            int n = col0 + wn * (TN / 2) + j * 16 + l16;
            if (n >= ncols) continue;
            if (EPI == 0) {
                for (int v = 0; v < 4; v++)
                    Cb[(size_t)(mb + v) * ldc + n] = f2b(acc[i][j][v]);
            } else if (EPI == 1) {
                float bv = b2f(bias[n]);
                for (int v = 0; v < 4; v++) {
                    float xx = acc[i][j][v] + bv;
                    // softplus: max(x,0) + log(1+exp(-|x|)); __logf is
                    // absolutely-accurate here (e<<1 only when |x| large)
                    dstf[(size_t)(mb + v) * ldc + n] =
                        fmaxf(xx, 0.f) + __logf(1.f + __expf(-fabsf(xx)));
                }
            } else {
                for (int v = 0; v < 4; v++)
                    dstf[(size_t)(mb + v) * ldc + n] = acc[i][j][v];
            }
        }
    }
}

template<int EPI, int TN>
__global__ __launch_bounds__(256) void gemm_bt(
    const u16* __restrict__ A, const u16* __restrict__ B,
    int Kc, int lda, int ldb,
    u16* __restrict__ Cb, float* __restrict__ Cf, int ldc, int ncols,
    const u16* __restrict__ bias, size_t zslab)
{
    gemm_core<EPI, TN>(blockIdx.x, blockIdx.y, blockIdx.z,
                       A, B, Kc, lda, ldb, Cb, Cf, ldc, ncols, bias, zslab);
}

// reduce 16 x_dbl split-K f32 slabs -> bf16 xdbl (2048 x 128)
__global__ __launch_bounds__(256) void redc_k(
    const float* __restrict__ part, u16* __restrict__ dst)
{
    int gid = blockIdx.x * 256 + threadIdx.x;   // 65536 total
    int idx = gid * 4;
    f32x4 s = {0.f, 0.f, 0.f, 0.f};
    for (int sl = 0; sl < 16; sl++) {
        f32x4 p = *(const f32x4*)&part[(size_t)sl * 262144 + idx];
        for (int e = 0; e < 4; e++) s[e] += p[e];
    }
    u16x4 o;
    for (int e = 0; e < 4; e++) o[e] = f2b(s[e]);
    *(u16x4*)&dst[idx] = o;
}

// ---------------- depthwise causal conv(4) + bias + SiLU ----------------
__global__ __launch_bounds__(256) void conv_silu_k(
    const u16* __restrict__ xr, const u16* __restrict__ cw,
    const u16* __restrict__ cb, u16* __restrict__ u)
{
    int tid = threadIdx.x;
    int bl  = blockIdx.x;       // b*1024 + l
    int l   = bl & 1023;
    int d0  = tid * 8;
    float acc[8];
    u16x8 bias = *(const u16x8*)&cb[d0];
    for (int j = 0; j < 8; j++) acc[j] = b2f(bias[j]);
    union { u16x8 v[4]; u16 s[32]; } wb;
    for (int t = 0; t < 4; t++) wb.v[t] = *(const u16x8*)&cw[d0 * 4 + t * 8];
    for (int t = 0; t < 4; t++) {
        int ls = l - 3 + t;
        if (ls < 0) continue;
        u16x8 xv = *(const u16x8*)&xr[(size_t)(bl - 3 + t) * 4096 + d0];
        for (int j = 0; j < 8; j++) acc[j] += b2f(xv[j]) * b2f(wb.s[j * 4 + t]);
    }
    u16x8 o;
    for (int j = 0; j < 8; j++) o[j] = f2b(silu_f(acc[j]));
    *(u16x8*)&u[(size_t)bl * 2048 + d0] = o;
}

// ---------------- fused: selective scan (blocks 0..511) + qkv (512..1007) ----------------
__global__ __launch_bounds__(256) void scan_qkv_k(
    const float* __restrict__ delta, const u16* __restrict__ u,
    const u16* __restrict__ xr, const u16* __restrict__ xdbl,
    const u16* __restrict__ latent, const u16* __restrict__ Alog,
    const u16* __restrict__ Dp, u16* __restrict__ yg,
    const u16* __restrict__ Wc, u16* __restrict__ q, u16* __restrict__ k,
    u16* __restrict__ v)
{
    __shared__ float sm[1024];
    int tid = threadIdx.x;
    int bid = blockIdx.x;
    if (bid < 512) {
        float (*Bs)[16] = (float(*)[16])sm;
        float (*Cs)[16] = (float(*)[16])(sm + 512);
        int dblk = bid & 7, bg = bid >> 3;       // bg = b*32+g
        int d = dblk * 256 + tid;
        for (int idx = tid; idx < 512; idx += 256) {
            int p = idx >> 4, n = idx & 15;
            const u16* xp = &xdbl[(size_t)(bg * 32 + p) * 128];
            Bs[p][n] = b2f(xp[64 + n]);
            Cs[p][n] = b2f(xp[80 + n]);
        }
        __syncthreads();
        float a[16], h[16];
        {
            u16x8 a0 = *(const u16x8*)&Alog[(size_t)d * 16];
            u16x8 a1 = *(const u16x8*)&Alog[(size_t)d * 16 + 8];
            u16x8 l0 = *(const u16x8*)&latent[((size_t)bg * 2048 + d) * 16];
            u16x8 l1 = *(const u16x8*)&latent[((size_t)bg * 2048 + d) * 16 + 8];
            for (int n = 0; n < 8; n++) {
                a[n] = -__expf(b2f(a0[n])); a[8 + n] = -__expf(b2f(a1[n]));
                h[n] = b2f(l0[n]);          h[8 + n] = b2f(l1[n]);
            }
        }
        float Dd = b2f(Dp[d]);
        for (int p = 0; p < 32; p++) {
            size_t row = (size_t)bg * 32 + p;
            float dlt = delta[row * 2048 + d];
            float uu  = b2f(u[row * 2048 + d]);
            float db  = dlt * uu;
            float y = 0.f;
            if (p == 0) {
                for (int n = 0; n < 16; n++) { h[n] += db * Bs[0][n]; y += h[n] * Cs[0][n]; }
            } else {
                for (int n = 0; n < 16; n++) {
                    float w = __expf(dlt * a[n]);
                    h[n] = w * h[n] + db * Bs[p][n];
                    y += h[n] * Cs[p][n];
                }
            }
            float rs = b2f(xr[row * 4096 + 2048 + d]);
            yg[row * 2048 + d] = f2b((y + uu * Dd) * silu_f(rs));
        }
    } else {
        float (*Ws)[16] = (float(*)[16])sm;
        for (int i = tid; i < 768; i += 256) Ws[i >> 4][i & 15] = b2f(Wc[i]);
        __syncthreads();
        int gid = (bid - 512) * 256 + tid;           // 126976 total
        int d = gid & 2047;
        int bi = gid >> 11;                          // b*31+i
        int b = bi / 31, i = bi - b * 31;
        const u16* lp = &latent[(((size_t)b * 32 + i) * 2048 + d) * 16];
        float lv[16];
        {
            u16x8 l0 = *(const u16x8*)lp, l1 = *(const u16x8*)(lp + 8);
            for (int m = 0; m < 8; m++) { lv[m] = b2f(l0[m]); lv[8 + m] = b2f(l1[m]); }
        }
        u16* outs[3] = {q, k, v};
        for (int pl = 0; pl < 3; pl++) {
            u16x8 o0, o1;
            for (int n = 0; n < 16; n++) {
                float s = 0.f;
                for (int m = 0; m < 16; m++) s += lv[m] * Ws[pl * 16 + n][m];
                if (n < 8) o0[n] = f2b(s); else o1[n - 8] = f2b(s);
            }
            u16* op = outs[pl] + (size_t)bi * 32768 + d * 16;
            *(u16x8*)op = o0; *(u16x8*)(op + 8) = o1;
        }
    }
}

// ---------------- fused: out-GEMM 128x64 split-K2 (blocks 0..511) + scores (512..2433) ----------------
__global__ __launch_bounds__(256) void gemm_scores_k(
    const u16* __restrict__ yg, const u16* __restrict__ Wout, float* __restrict__ out_part,
    const u16* __restrict__ q, const u16* __restrict__ kk, float* __restrict__ sc)
{
    int bid = blockIdx.x;
    if (bid < 512) {
        int bx = bid & 15, by = (bid >> 4) & 15, bz = bid >> 8;
        gemm_core<2, 64>(bx, by, bz, yg, Wout, 1024, 2048, 2048,
                         nullptr, out_part, 1024, 1024, nullptr, (size_t)2048 * 1024);
        return;
    }
    int idx = bid - 512;             // b*961 + i*31 + j
    int b = idx / 961, r = idx - b * 961;
    int i = r / 31, j = r - i * 31;
    if (j > i) return;
    const u16* qp = q + ((size_t)b * 31 + i) * 32768;
    const u16* kp = kk + ((size_t)b * 31 + j) * 32768;
    float s = 0.f;
    for (int t = threadIdx.x * 8; t < 32768; t += 2048) {
        u16x8 a = *(const u16x8*)&qp[t];
        u16x8 c = *(const u16x8*)&kp[t];
        for (int e = 0; e < 8; e++) s += b2f(a[e]) * b2f(c[e]);
    }
    for (int off = 32; off; off >>= 1) s += __shfl_xor(s, off);
    __shared__ float red[4];
    if ((threadIdx.x & 63) == 0) red[threadIdx.x >> 6] = s;
    __syncthreads();
    if (threadIdx.x == 0)
        sc[idx] = (red[0] + red[1] + red[2] + red[3]) * 5.5242717e-3f; // 1/sqrt(32768)
}

// ---------------- fused epilogue: attv+softmax (0..1023) + redout KS=2 (1024..3071) ----------------
__global__ __launch_bounds__(256) void attv_redout_k(
    const float* __restrict__ sc, const u16* __restrict__ v,
    const float* __restrict__ part, void* __restrict__ dout,
    const u16* __restrict__ xraw)
{
    int flag = dtype_flag_block(xraw);
    int bid = blockIdx.x;
    if (bid < 1024) {
        int chunk = bid & 15, bi = bid >> 4;
        int b = bi >> 5, i = (bi & 31) - 1;   // i = -1 -> zero row (group 0)
        __shared__ float as[32];
        if (i >= 0 && threadIdx.x < 64) {
            float x = (threadIdx.x <= i) ? sc[(size_t)b * 961 + i * 31 + threadIdx.x] : -3.4e38f;
            float mx = x;
            for (int off = 32; off; off >>= 1) mx = fmaxf(mx, __shfl_xor(mx, off));
            float e = (threadIdx.x <= i) ? __expf(x - mx) : 0.f;
            float sm = e;
            for (int off = 32; off; off >>= 1) sm += __shfl_xor(sm, off);
            if (threadIdx.x < 32) as[threadIdx.x] = e / sm;
        }
        __syncthreads();
        int dn = chunk * 2048 + threadIdx.x * 8;
        float acc[8] = {0, 0, 0, 0, 0, 0, 0, 0};
        if (i >= 0) {
            for (int j = 0; j <= i; j++) {
                u16x8 vv = *(const u16x8*)&v[((size_t)b * 31 + j) * 32768 + dn];
                float aj = as[j];
                for (int e = 0; e < 8; e++) acc[e] += aj * b2f(vv[e]);
            }
            for (int e = 0; e < 8; e++) if (!(fabsf(acc[e]) < 1e30f)) acc[e] = 0.f;
        }
        size_t ofs = 2097152 + ((size_t)b * 32 + (i + 1)) * 32768 + dn;
        if (flag) {
            f32x4 o0, o1;
            for (int e = 0; e < 4; e++) { o0[e] = acc[e]; o1[e] = acc[4 + e]; }
            *(f32x4*)((float*)dout + ofs) = o0;
            *(f32x4*)((float*)dout + ofs + 4) = o1;
        } else {
            u16x8 o;
            for (int e = 0; e < 8; e++) o[e] = f2b(acc[e]);
            *(u16x8*)((u16*)dout + ofs) = o;
        }
    } else {
        int gid = (bid - 1024) * 256 + threadIdx.x;   // 524288 total
        int m = gid >> 8;
        int j = (gid & 255) * 4;
        f32x4 s = {0.f, 0.f, 0.f, 0.f};
        for (int ks = 0; ks < 2; ks++) {
            f32x4 p = *(const f32x4*)&part[((size_t)ks * 2048 + m) * 1024 + j];
            for (int e = 0; e < 4; e++) s[e] += p[e];
        }
        for (int e = 0; e < 4; e++) if (!(fabsf(s[e]) < 1e30f)) s[e] = 0.f;
        if (flag) {
            ((f32x4*)dout)[(size_t)m * 256 + (j >> 2)] = s;
        } else {
            u16x4 o;
            for (int e = 0; e < 4; e++) o[e] = f2b(s[e]);
            ((u16x4*)dout)[(size_t)m * 256 + (j >> 2)] = o;
        }
    }
}

extern "C" void kernel_launch(void* const* d_in, const int* in_sizes, int n_in,
                              void* d_out, int out_size, void* d_ws, size_t ws_size,
                              hipStream_t stream)
{
    char* ws = (char*)d_ws;
    const u16* xraw = (const u16*)d_in[0];
    // canonical bf16 inputs
    u16* cx    = (u16*)(ws + 0);
    u16* clat  = (u16*)(ws + 4194304);
    u16* cWin  = (u16*)(ws + 8388608);
    u16* ccw   = (u16*)(ws + 16777216);
    u16* ccb   = (u16*)(ws + 16793600);
    u16* wxp   = (u16*)(ws + 16797696);   // 128x2048 (W_x + zero pad)
    u16* cWdt  = (u16*)(ws + 17321984);
    u16* cbdt  = (u16*)(ws + 17584128);
    u16* cWout = (u16*)(ws + 17588224);
    u16* cAlog = (u16*)(ws + 21782528);
    u16* cD    = (u16*)(ws + 21848064);
    u16* cWc   = (u16*)(ws + 21852160);
    // intermediates (private; ws ~268 MB)
    float* xdbl_part = (float*)(ws + 21853760);  // 16 x 2048x128 f32 slabs
    u16*   xdbl      = (u16*)(ws + 38630976);    // 2048x128 bf16 (reduced)
    float* sc        = (float*)(ws + 39155264);  // 1922 f32
    u16*   u         = (u16*)(ws + 39163008);    // 2048x2048 bf16
    u16*   xr        = (u16*)(ws + 47551616);    // 2048x4096 bf16
    u16*   yg        = (u16*)(ws + 64328832);    // 2048x2048 bf16
    float* delta     = (float*)(ws + 72717440);  // 2048x2048 f32
    u16*   qb        = (u16*)(ws + 89494656);    // 3x 2031616 bf16
    u16*   kb        = qb + 2031616;
    u16*   vb        = kb + 2031616;
    float* out_part  = (float*)(ws + 101684352); // 2x2048x1024 f32 (ends ~118 MB)

    // 1) canonicalize inputs to bf16
    CvtArgs ca;
    const void* srcs[13] = { d_in[0], d_in[1], d_in[2], d_in[3], d_in[4],
                             d_in[5], nullptr, d_in[6], d_in[7], d_in[8],
                             d_in[9], d_in[10], d_in[11] };
    u16* dsts[13] = { cx, clat, cWin, ccw, ccb,
                      wxp, wxp + 196608, cWdt, cbdt, cWout,
                      cAlog, cD, cWc };
    int ns[13] = { 2097152, 2097152, 4194304, 8192, 2048,
                   196608, 65536, 131072, 2048, 2097152,
                   32768, 2048, 768 };
    int cum = 0;
    for (int i = 0; i < 13; i++) {
        ca.s[i] = srcs[i]; ca.d[i] = dsts[i];
        ca.cum[i] = cum; cum += ns[i] / 4;
    }
    ca.cum[13] = cum; ca.total = cum;    // 2,731,712 units
    cvt_all_k<<<(cum + 255) / 256, 256, 0, stream>>>(ca, xraw);

    // 2) xr = x @ W_in^T (M=2048,N=4096,K=1024), 128x64 tiles -> 1024 blocks
    gemm_bt<0, 64><<<dim3(64, 16, 1), 256, 0, stream>>>(cx, cWin, 1024, 1024, 1024,
                                                        xr, nullptr, 4096, 4096, nullptr, 0);
    // 3) depthwise conv + SiLU
    conv_silu_k<<<2048, 256, 0, stream>>>(xr, ccw, ccb, u);
    // 4) x_dbl = u @ W_x^T, split-K 16 -> f32 slabs, 128x64 tiles -> 512 blocks
    gemm_bt<2, 64><<<dim3(2, 16, 16), 256, 0, stream>>>(u, wxp, 128, 2048, 2048,
                                                        nullptr, xdbl_part, 128, 128,
                                                        nullptr, 262144);
    // 5) reduce 16 slabs -> xdbl bf16 (2048x128)
    redc_k<<<256, 256, 0, stream>>>(xdbl_part, xdbl);
    // 6) delta = softplus(xdbl[:,:64] @ W_dt^T + b_dt), 128x64 tiles -> 512 blocks
    gemm_bt<1, 64><<<dim3(32, 16, 1), 256, 0, stream>>>(xdbl, cWdt, 64, 128, 64,
                                                        nullptr, delta, 2048, 2048, cbdt, 0);
    // 7) selective scan + gating (blocks 0..511) | qkv (512..1007)
    scan_qkv_k<<<1008, 256, 0, stream>>>(delta, u, xr, xdbl, clat, cAlog, cD, yg,
                                         cWc, qb, kb, vb);
    // 8) out-GEMM 128x64 split-K2 (blocks 0..511) | scores (512..2433)
    gemm_scores_k<<<2434, 256, 0, stream>>>(yg, cWout, out_part, qb, kb, sc);
    // 9) attv+softmax -> d_out[2097152:] | split-K reduce -> d_out[0:2097152]
    attv_redout_k<<<3072, 256, 0, stream>>>(sc, vb, out_part, d_out, xraw);
}

// Round 10
// 224.881 us; speedup vs baseline: 1.7364x; 1.0072x over previous
//
#include <hip/hip_runtime.h>
#include <stdint.h>

typedef uint16_t u16;
typedef u16   u16x4  __attribute__((ext_vector_type(4)));
typedef u16   u16x8  __attribute__((ext_vector_type(8)));
typedef __bf16 bf16x8 __attribute__((ext_vector_type(8)));
typedef float f32x4  __attribute__((ext_vector_type(4)));

__device__ __forceinline__ float b2f(u16 x) {
    union { uint32_t u; float f; } c; c.u = ((uint32_t)x) << 16; return c.f;
}
__device__ __forceinline__ u16 f2b(float f) {
    union { float f; uint32_t u; } c; c.f = f;
    uint32_t r = c.u + 0x7FFFu + ((c.u >> 16) & 1u);
    return (u16)(r >> 16);
}
__device__ __forceinline__ float silu_f(float x) { return x / (1.f + __expf(-x)); }
__device__ __forceinline__ float softplus_f(float x) {
    return fmaxf(x, 0.f) + __logf(1.f + __expf(-fabsf(x)));
}

__device__ __forceinline__ void gload16(const u16* g, u16* l) {
    __builtin_amdgcn_global_load_lds(
        (const __attribute__((address_space(1))) void*)(g),
        (__attribute__((address_space(3))) void*)(l), 16, 0, 0);
}

// per-block dtype flag: 1 = f32 inputs, 0 = bf16. Contains barriers; call first.
__device__ __forceinline__ int dtype_flag_block(const u16* __restrict__ xraw) {
    __shared__ int bad;
    if (threadIdx.x == 0) bad = 0;
    __syncthreads();
    float v = b2f(xraw[threadIdx.x]);
    if (!(fabsf(v) < 1000.f)) atomicAdd(&bad, 1);   // NaN-safe
    __syncthreads();
    return bad;
}

// ---------------- unified input canonicalization (13 segments) ----------------
struct CvtArgs {
    const void* s[13];
    u16* d[13];
    int cum[14];
    int total;
};
__global__ __launch_bounds__(256) void cvt_all_k(CvtArgs a, const u16* __restrict__ xraw)
{
    int flag = dtype_flag_block(xraw);
    int u4 = blockIdx.x * 256 + threadIdx.x;
    if (u4 >= a.total) return;
    int seg = 0;
    while (u4 >= a.cum[seg + 1]) seg++;
    int local = u4 - a.cum[seg];
    const void* s = a.s[seg];
    u16x4 o;
    if (s == nullptr) {
        o[0] = o[1] = o[2] = o[3] = 0;
    } else if (flag) {
        f32x4 vv = ((const f32x4*)s)[local];
        for (int e = 0; e < 4; e++) o[e] = f2b(vv[e]);
    } else {
        o = ((const u16x4*)s)[local];
    }
    *(u16x4*)(a.d[seg] + (size_t)local * 4) = o;
}

// ---------------- MFMA NT GEMM core: C[m,n] = sum_k A[m,k]*B[n,k] ----------------
// 128(M) x TN(N) tile, BK=64, 4 waves (2x2), swizzled LDS slots.
// Async global_load_lds staging. EPI 0: bf16 store. 2: f32 partial at
// Cf + z*zslab. Kc multiple of 64.
template<int EPI, int TN>
__device__ __forceinline__ void gemm_core(
    int bx, int by, int bz,
    const u16* __restrict__ A, const u16* __restrict__ B,
    int Kc, int lda, int ldb,
    u16* __restrict__ Cb, float* __restrict__ Cf, int ldc, int ncols,
    size_t zslab)
{
    constexpr int NJ = TN / 32;
    constexpr int BT = TN / 32;
    __shared__ __align__(16) u16 lA[128 * 64];
    __shared__ __align__(16) u16 lB[TN * 64];
    const int tid  = threadIdx.x;
    const int wave = tid >> 6, lane = tid & 63;
    const int quad = lane >> 4, l16 = lane & 15;
    const int wm = wave & 1, wn = wave >> 1;
    const int row0 = by * 128, col0 = bx * TN;
    const int kbeg = bz * Kc;

    f32x4 acc[4][NJ];
    const f32x4 zf = {0.f, 0.f, 0.f, 0.f};
    for (int i = 0; i < 4; i++) for (int j = 0; j < NJ; j++) acc[i][j] = zf;

    // chunk c: 16B at lX[c*8]; row r=c>>3, slot s=c&7 holds k-group
    // q=(s-(r>>1))&7 (bank swizzle).
    const u16* Ap[4]; const u16* Bp[BT];
    int lbaseA[4], lbaseB[BT];
    for (int t = 0; t < 4; t++) {
        int c = t * 256 + tid;
        int r = c >> 3, s = c & 7;
        int q = (s - (r >> 1)) & 7;
        Ap[t] = A + (size_t)(row0 + r) * lda + q * 8 + kbeg;
        lbaseA[t] = (t * 256 + wave * 64) * 8;
    }
    for (int t = 0; t < BT; t++) {
        int c = t * 256 + tid;
        int r = c >> 3, s = c & 7;
        int q = (s - (r >> 1)) & 7;
        Bp[t] = B + (size_t)(col0 + r) * ldb + q * 8 + kbeg;
        lbaseB[t] = (t * 256 + wave * 64) * 8;
    }

    for (int k0 = 0; k0 < Kc; k0 += 64) {
        for (int t = 0; t < 4; t++) gload16(Ap[t] + k0, &lA[lbaseA[t]]);
        for (int t = 0; t < BT; t++) gload16(Bp[t] + k0, &lB[lbaseB[t]]);
        __syncthreads();
        for (int half = 0; half < 2; half++) {
            bf16x8 af[4], bfr[NJ];
            for (int i = 0; i < 4; i++) {
                int r = wm * 64 + i * 16 + l16;
                int s = (half * 4 + quad + (r >> 1)) & 7;
                af[i] = *(const bf16x8*)&lA[r * 64 + s * 8];
            }
            for (int j = 0; j < NJ; j++) {
                int r = wn * (TN / 2) + j * 16 + l16;
                int s = (half * 4 + quad + (r >> 1)) & 7;
                bfr[j] = *(const bf16x8*)&lB[r * 64 + s * 8];
            }
            for (int i = 0; i < 4; i++)
                for (int j = 0; j < NJ; j++)
                    acc[i][j] = __builtin_amdgcn_mfma_f32_16x16x32_bf16(af[i], bfr[j], acc[i][j], 0, 0, 0);
        }
        __syncthreads();
    }

    float* dstf = (EPI == 2) ? (Cf + (size_t)bz * zslab) : Cf;
    for (int i = 0; i < 4; i++) {
        int mb = row0 + wm * 64 + i * 16 + quad * 4;
        for (int j = 0; j < NJ; j++) {
            int n = col0 + wn * (TN / 2) + j * 16 + l16;
            if (n >= ncols) continue;
            if (EPI == 0) {
                for (int v = 0; v < 4; v++)
                    Cb[(size_t)(mb + v) * ldc + n] = f2b(acc[i][j][v]);
            } else {
                for (int v = 0; v < 4; v++)
                    dstf[(size_t)(mb + v) * ldc + n] = acc[i][j][v];
            }
        }
    }
}

template<int EPI, int TN>
__global__ __launch_bounds__(256) void gemm_bt(
    const u16* __restrict__ A, const u16* __restrict__ B,
    int Kc, int lda, int ldb,
    u16* __restrict__ Cb, float* __restrict__ Cf, int ldc, int ncols,
    size_t zslab)
{
    gemm_core<EPI, TN>(blockIdx.x, blockIdx.y, blockIdx.z,
                       A, B, Kc, lda, ldb, Cb, Cf, ldc, ncols, zslab);
}

// reduce 16 x_dbl split-K f32 slabs -> bf16 xdbl (2048 x 128)
__global__ __launch_bounds__(256) void redc_k(
    const float* __restrict__ part, u16* __restrict__ dst)
{
    int gid = blockIdx.x * 256 + threadIdx.x;   // 65536 total
    int idx = gid * 4;
    f32x4 s = {0.f, 0.f, 0.f, 0.f};
    for (int sl = 0; sl < 16; sl++) {
        f32x4 p = *(const f32x4*)&part[(size_t)sl * 262144 + idx];
        for (int e = 0; e < 4; e++) s[e] += p[e];
    }
    u16x4 o;
    for (int e = 0; e < 4; e++) o[e] = f2b(s[e]);
    *(u16x4*)&dst[idx] = o;
}

// ---------------- depthwise causal conv(4) + bias + SiLU ----------------
__global__ __launch_bounds__(256) void conv_silu_k(
    const u16* __restrict__ xr, const u16* __restrict__ cw,
    const u16* __restrict__ cb, u16* __restrict__ u)
{
    int tid = threadIdx.x;
    int bl  = blockIdx.x;       // b*1024 + l
    int l   = bl & 1023;
    int d0  = tid * 8;
    float acc[8];
    u16x8 bias = *(const u16x8*)&cb[d0];
    for (int j = 0; j < 8; j++) acc[j] = b2f(bias[j]);
    union { u16x8 v[4]; u16 s[32]; } wb;
    for (int t = 0; t < 4; t++) wb.v[t] = *(const u16x8*)&cw[d0 * 4 + t * 8];
    for (int t = 0; t < 4; t++) {
        int ls = l - 3 + t;
        if (ls < 0) continue;
        u16x8 xv = *(const u16x8*)&xr[(size_t)(bl - 3 + t) * 4096 + d0];
        for (int j = 0; j < 8; j++) acc[j] += b2f(xv[j]) * b2f(wb.s[j * 4 + t]);
    }
    u16x8 o;
    for (int j = 0; j < 8; j++) o[j] = f2b(silu_f(acc[j]));
    *(u16x8*)&u[(size_t)bl * 2048 + d0] = o;
}

// ---------------- fused: scan w/ inline delta-MFMA (blocks 0..511) + qkv (512..1007) ----------------
// Per scan block (bg, dblk): delta[32p x 256d] = softplus(xdbl[:, :64] @ Wdt^T + bdt)
// computed via 16x16x32 MFMA into LDS, then the 32-step scan reads it from LDS.
__global__ __launch_bounds__(256) void scan_qkv_k(
    const u16* __restrict__ u, const u16* __restrict__ xr,
    const u16* __restrict__ xdbl, const u16* __restrict__ Wdt,
    const u16* __restrict__ bdt,
    const u16* __restrict__ latent, const u16* __restrict__ Alog,
    const u16* __restrict__ Dp, u16* __restrict__ yg,
    const u16* __restrict__ Wc, u16* __restrict__ q, u16* __restrict__ k,
    u16* __restrict__ v)
{
    // LDS (u16 units): lA[0,2048) 4KB | lB[2048,18432) 32KB |
    //                  dls f32 [18432,34816) 32KB | Bs/Cs [34816,36864) 4KB
    __shared__ __align__(16) u16 lsh[36864];    // 72KB
    int tid = threadIdx.x;
    int bid = blockIdx.x;
    if (bid < 512) {
        u16* lA = lsh;
        u16* lB = lsh + 2048;
        float* dls = (float*)(lsh + 18432);     // [32][256]
        float (*Bs)[16] = (float(*)[16])(lsh + 34816);
        float (*Cs)[16] = (float(*)[16])(lsh + 35840);
        const int wave = tid >> 6, lane = tid & 63;
        const int quad = lane >> 4, l16 = lane & 15;
        int dblk = bid & 7, bg = bid >> 3;       // bg = b*32+g
        int d = dblk * 256 + tid;

        // stage A = xdbl[bg's 32 rows][0:64] (swizzled chunks, 1/thread)
        {
            int r = tid >> 3, s = tid & 7;
            int qg = (s - (r >> 1)) & 7;
            gload16(&xdbl[(size_t)(bg * 32 + r) * 128 + qg * 8], &lA[(wave * 64) * 8]);
        }
        // stage B = Wdt rows [dblk*256, +256) (8 chunks/thread)
        for (int t = 0; t < 8; t++) {
            int c = t * 256 + tid;
            int r = c >> 3, s = c & 7;
            int qg = (s - (r >> 1)) & 7;
            gload16(&Wdt[(size_t)(dblk * 256 + r) * 64 + qg * 8],
                    &lB[(t * 256 + wave * 64) * 8]);
        }
        // B/C tiles from xdbl cols 64..96
        for (int idx = tid; idx < 512; idx += 256) {
            int p = idx >> 4, n = idx & 15;
            const u16* xp = &xdbl[(size_t)(bg * 32 + p) * 128];
            Bs[p][n] = b2f(xp[64 + n]);
            Cs[p][n] = b2f(xp[80 + n]);
        }
        __syncthreads();

        // delta MFMA: C[32p x 256d], wave covers 64 d-cols, 2 p-subtiles x 4 d-subtiles
        f32x4 dacc[2][4];
        const f32x4 zf = {0.f, 0.f, 0.f, 0.f};
        for (int i = 0; i < 2; i++) for (int j = 0; j < 4; j++) dacc[i][j] = zf;
        for (int half = 0; half < 2; half++) {
            bf16x8 af[2], bfr[4];
            for (int i = 0; i < 2; i++) {
                int r = i * 16 + l16;
                int s = (half * 4 + quad + (r >> 1)) & 7;
                af[i] = *(const bf16x8*)&lA[r * 64 + s * 8];
            }
            for (int j = 0; j < 4; j++) {
                int r = wave * 64 + j * 16 + l16;
                int s = (half * 4 + quad + (r >> 1)) & 7;
                bfr[j] = *(const bf16x8*)&lB[r * 64 + s * 8];
            }
            for (int i = 0; i < 2; i++)
                for (int j = 0; j < 4; j++)
                    dacc[i][j] = __builtin_amdgcn_mfma_f32_16x16x32_bf16(af[i], bfr[j], dacc[i][j], 0, 0, 0);
        }
        // softplus epilogue -> dls[p][dlocal]
        for (int j = 0; j < 4; j++) {
            int n = wave * 64 + j * 16 + l16;
            float bv = b2f(bdt[dblk * 256 + n]);
            for (int i = 0; i < 2; i++) {
                int mb = i * 16 + quad * 4;
                for (int vv = 0; vv < 4; vv++)
                    dls[(mb + vv) * 256 + n] = softplus_f(dacc[i][j][vv] + bv);
            }
        }
        __syncthreads();

        float a[16], h[16];
        {
            u16x8 a0 = *(const u16x8*)&Alog[(size_t)d * 16];
            u16x8 a1 = *(const u16x8*)&Alog[(size_t)d * 16 + 8];
            u16x8 l0 = *(const u16x8*)&latent[((size_t)bg * 2048 + d) * 16];
            u16x8 l1 = *(const u16x8*)&latent[((size_t)bg * 2048 + d) * 16 + 8];
            for (int n = 0; n < 8; n++) {
                a[n] = -__expf(b2f(a0[n])); a[8 + n] = -__expf(b2f(a1[n]));
                h[n] = b2f(l0[n]);          h[8 + n] = b2f(l1[n]);
            }
        }
        float Dd = b2f(Dp[d]);
        for (int p = 0; p < 32; p++) {
            size_t row = (size_t)bg * 32 + p;
            float dlt = dls[p * 256 + tid];
            float uu  = b2f(u[row * 2048 + d]);
            float db  = dlt * uu;
            float y = 0.f;
            if (p == 0) {
                for (int n = 0; n < 16; n++) { h[n] += db * Bs[0][n]; y += h[n] * Cs[0][n]; }
            } else {
                for (int n = 0; n < 16; n++) {
                    float w = __expf(dlt * a[n]);
                    h[n] = w * h[n] + db * Bs[p][n];
                    y += h[n] * Cs[p][n];
                }
            }
            float rs = b2f(xr[row * 4096 + 2048 + d]);
            yg[row * 2048 + d] = f2b((y + uu * Dd) * silu_f(rs));
        }
    } else {
        float (*Ws)[16] = (float(*)[16])lsh;
        for (int i = tid; i < 768; i += 256) Ws[i >> 4][i & 15] = b2f(Wc[i]);
        __syncthreads();
        int gid = (bid - 512) * 256 + tid;           // 126976 total
        int d = gid & 2047;
        int bi = gid >> 11;                          // b*31+i
        int b = bi / 31, i = bi - b * 31;
        const u16* lp = &latent[(((size_t)b * 32 + i) * 2048 + d) * 16];
        float lv[16];
        {
            u16x8 l0 = *(const u16x8*)lp, l1 = *(const u16x8*)(lp + 8);
            for (int m = 0; m < 8; m++) { lv[m] = b2f(l0[m]); lv[8 + m] = b2f(l1[m]); }
        }
        u16* outs[3] = {q, k, v};
        for (int pl = 0; pl < 3; pl++) {
            u16x8 o0, o1;
            for (int n = 0; n < 16; n++) {
                float s = 0.f;
                for (int m = 0; m < 16; m++) s += lv[m] * Ws[pl * 16 + n][m];
                if (n < 8) o0[n] = f2b(s); else o1[n - 8] = f2b(s);
            }
            u16* op = outs[pl] + (size_t)bi * 32768 + d * 16;
            *(u16x8*)op = o0; *(u16x8*)(op + 8) = o1;
        }
    }
}

// ---------------- fused: out-GEMM 128x64 split-K2 (blocks 0..511) + scores (512..2433) ----------------
__global__ __launch_bounds__(256) void gemm_scores_k(
    const u16* __restrict__ yg, const u16* __restrict__ Wout, float* __restrict__ out_part,
    const u16* __restrict__ q, const u16* __restrict__ kk, float* __restrict__ sc)
{
    int bid = blockIdx.x;
    if (bid < 512) {
        int bx = bid & 15, by = (bid >> 4) & 15, bz = bid >> 8;
        gemm_core<2, 64>(bx, by, bz, yg, Wout, 1024, 2048, 2048,
                         nullptr, out_part, 1024, 1024, (size_t)2048 * 1024);
        return;
    }
    int idx = bid - 512;             // b*961 + i*31 + j
    int b = idx / 961, r = idx - b * 961;
    int i = r / 31, j = r - i * 31;
    if (j > i) return;
    const u16* qp = q + ((size_t)b * 31 + i) * 32768;
    const u16* kp = kk + ((size_t)b * 31 + j) * 32768;
    float s = 0.f;
    for (int t = threadIdx.x * 8; t < 32768; t += 2048) {
        u16x8 a = *(const u16x8*)&qp[t];
        u16x8 c = *(const u16x8*)&kp[t];
        for (int e = 0; e < 8; e++) s += b2f(a[e]) * b2f(c[e]);
    }
    for (int off = 32; off; off >>= 1) s += __shfl_xor(s, off);
    __shared__ float red[4];
    if ((threadIdx.x & 63) == 0) red[threadIdx.x >> 6] = s;
    __syncthreads();
    if (threadIdx.x == 0)
        sc[idx] = (red[0] + red[1] + red[2] + red[3]) * 5.5242717e-3f; // 1/sqrt(32768)
}

// ---------------- fused epilogue: attv+softmax (0..1023) + redout KS=2 (1024..3071) ----------------
__global__ __launch_bounds__(256) void attv_redout_k(
    const float* __restrict__ sc, const u16* __restrict__ v,
    const float* __restrict__ part, void* __restrict__ dout,
    const u16* __restrict__ xraw)
{
    int flag = dtype_flag_block(xraw);
    int bid = blockIdx.x;
    if (bid < 1024) {
        int chunk = bid & 15, bi = bid >> 4;
        int b = bi >> 5, i = (bi & 31) - 1;   // i = -1 -> zero row (group 0)
        __shared__ float as[32];
        if (i >= 0 && threadIdx.x < 64) {
            float x = (threadIdx.x <= i) ? sc[(size_t)b * 961 + i * 31 + threadIdx.x] : -3.4e38f;
            float mx = x;
            for (int off = 32; off; off >>= 1) mx = fmaxf(mx, __shfl_xor(mx, off));
            float e = (threadIdx.x <= i) ? __expf(x - mx) : 0.f;
            float sm = e;
            for (int off = 32; off; off >>= 1) sm += __shfl_xor(sm, off);
            if (threadIdx.x < 32) as[threadIdx.x] = e / sm;
        }
        __syncthreads();
        int dn = chunk * 2048 + threadIdx.x * 8;
        float acc[8] = {0, 0, 0, 0, 0, 0, 0, 0};
        if (i >= 0) {
            for (int j = 0; j <= i; j++) {
                u16x8 vv = *(const u16x8*)&v[((size_t)b * 31 + j) * 32768 + dn];
                float aj = as[j];
                for (int e = 0; e < 8; e++) acc[e] += aj * b2f(vv[e]);
            }
            for (int e = 0; e < 8; e++) if (!(fabsf(acc[e]) < 1e30f)) acc[e] = 0.f;
        }
        size_t ofs = 2097152 + ((size_t)b * 32 + (i + 1)) * 32768 + dn;
        if (flag) {
            f32x4 o0, o1;
            for (int e = 0; e < 4; e++) { o0[e] = acc[e]; o1[e] = acc[4 + e]; }
            *(f32x4*)((float*)dout + ofs) = o0;
            *(f32x4*)((float*)dout + ofs + 4) = o1;
        } else {
            u16x8 o;
            for (int e = 0; e < 8; e++) o[e] = f2b(acc[e]);
            *(u16x8*)((u16*)dout + ofs) = o;
        }
    } else {
        int gid = (bid - 1024) * 256 + threadIdx.x;   // 524288 total
        int m = gid >> 8;
        int j = (gid & 255) * 4;
        f32x4 s = {0.f, 0.f, 0.f, 0.f};
        for (int ks = 0; ks < 2; ks++) {
            f32x4 p = *(const f32x4*)&part[((size_t)ks * 2048 + m) * 1024 + j];
            for (int e = 0; e < 4; e++) s[e] += p[e];
        }
        for (int e = 0; e < 4; e++) if (!(fabsf(s[e]) < 1e30f)) s[e] = 0.f;
        if (flag) {
            ((f32x4*)dout)[(size_t)m * 256 + (j >> 2)] = s;
        } else {
            u16x4 o;
            for (int e = 0; e < 4; e++) o[e] = f2b(s[e]);
            ((u16x4*)dout)[(size_t)m * 256 + (j >> 2)] = o;
        }
    }
}

extern "C" void kernel_launch(void* const* d_in, const int* in_sizes, int n_in,
                              void* d_out, int out_size, void* d_ws, size_t ws_size,
                              hipStream_t stream)
{
    char* ws = (char*)d_ws;
    const u16* xraw = (const u16*)d_in[0];
    // canonical bf16 inputs
    u16* cx    = (u16*)(ws + 0);
    u16* clat  = (u16*)(ws + 4194304);
    u16* cWin  = (u16*)(ws + 8388608);
    u16* ccw   = (u16*)(ws + 16777216);
    u16* ccb   = (u16*)(ws + 16793600);
    u16* wxp   = (u16*)(ws + 16797696);   // 128x2048 (W_x + zero pad)
    u16* cWdt  = (u16*)(ws + 17321984);
    u16* cbdt  = (u16*)(ws + 17584128);
    u16* cWout = (u16*)(ws + 17588224);
    u16* cAlog = (u16*)(ws + 21782528);
    u16* cD    = (u16*)(ws + 21848064);
    u16* cWc   = (u16*)(ws + 21852160);
    // intermediates (private; ws ~268 MB)
    float* xdbl_part = (float*)(ws + 21853760);  // 16 x 2048x128 f32 slabs
    u16*   xdbl      = (u16*)(ws + 38630976);    // 2048x128 bf16 (reduced)
    float* sc        = (float*)(ws + 39155264);  // 1922 f32
    u16*   u         = (u16*)(ws + 39163008);    // 2048x2048 bf16
    u16*   xr        = (u16*)(ws + 47551616);    // 2048x4096 bf16
    u16*   yg        = (u16*)(ws + 64328832);    // 2048x2048 bf16
    u16*   qb        = (u16*)(ws + 72717440);    // 3x 2031616 bf16
    u16*   kb        = qb + 2031616;
    u16*   vb        = kb + 2031616;
    float* out_part  = (float*)(ws + 84907136);  // 2x2048x1024 f32 (ends ~102 MB)

    // 1) canonicalize inputs to bf16
    CvtArgs ca;
    const void* srcs[13] = { d_in[0], d_in[1], d_in[2], d_in[3], d_in[4],
                             d_in[5], nullptr, d_in[6], d_in[7], d_in[8],
                             d_in[9], d_in[10], d_in[11] };
    u16* dsts[13] = { cx, clat, cWin, ccw, ccb,
                      wxp, wxp + 196608, cWdt, cbdt, cWout,
                      cAlog, cD, cWc };
    int ns[13] = { 2097152, 2097152, 4194304, 8192, 2048,
                   196608, 65536, 131072, 2048, 2097152,
                   32768, 2048, 768 };
    int cum = 0;
    for (int i = 0; i < 13; i++) {
        ca.s[i] = srcs[i]; ca.d[i] = dsts[i];
        ca.cum[i] = cum; cum += ns[i] / 4;
    }
    ca.cum[13] = cum; ca.total = cum;    // 2,731,712 units
    cvt_all_k<<<(cum + 255) / 256, 256, 0, stream>>>(ca, xraw);

    // 2) xr = x @ W_in^T (M=2048,N=4096,K=1024), 128x64 tiles -> 1024 blocks
    gemm_bt<0, 64><<<dim3(64, 16, 1), 256, 0, stream>>>(cx, cWin, 1024, 1024, 1024,
                                                        xr, nullptr, 4096, 4096, 0);
    // 3) depthwise conv + SiLU
    conv_silu_k<<<2048, 256, 0, stream>>>(xr, ccw, ccb, u);
    // 4) x_dbl = u @ W_x^T, split-K 16 -> f32 slabs, 128x64 tiles -> 512 blocks
    gemm_bt<2, 64><<<dim3(2, 16, 16), 256, 0, stream>>>(u, wxp, 128, 2048, 2048,
                                                        nullptr, xdbl_part, 128, 128,
                                                        262144);
    // 5) reduce 16 slabs -> xdbl bf16 (2048x128)
    redc_k<<<256, 256, 0, stream>>>(xdbl_part, xdbl);
    // 6) scan w/ inline delta MFMA (blocks 0..511) | qkv (512..1007)
    scan_qkv_k<<<1008, 256, 0, stream>>>(u, xr, xdbl, cWdt, cbdt, clat, cAlog, cD, yg,
                                         cWc, qb, kb, vb);
    // 7) out-GEMM 128x64 split-K2 (blocks 0..511) | scores (512..2433)
    gemm_scores_k<<<2434, 256, 0, stream>>>(yg, cWout, out_part, qb, kb, sc);
    // 8) attv+softmax -> d_out[2097152:] | split-K reduce -> d_out[0:2097152]
    attv_redout_k<<<3072, 256, 0, stream>>>(sc, vb, out_part, d_out, xraw);
}